// Round 16
// baseline (470.130 us; speedup 1.0000x reference)
//
#include <hip/hip_runtime.h>

#define B_ 4
#define S_ 1024
#define H_ 1024
#define NH_ 16
#define DK_ 64
#define MLPH_ 4096
#define EPS_ 1e-5f

typedef __attribute__((ext_vector_type(8))) short short8_t;
typedef __attribute__((ext_vector_type(8))) unsigned short ushort8_t;
typedef __attribute__((ext_vector_type(4))) float f32x4;

__device__ __forceinline__ unsigned short f2bf(float f) {
  unsigned int u = __float_as_uint(f);
  u = u + 0x7fffu + ((u >> 16) & 1u);  // RNE
  return (unsigned short)(u >> 16);
}
__device__ __forceinline__ float bf2f(unsigned short b) {
  return __uint_as_float(((unsigned int)b) << 16);
}

__device__ __forceinline__ void gload16(const void* g, void* l) {
  typedef const __attribute__((address_space(1))) unsigned int GU;
  typedef __attribute__((address_space(3))) unsigned int LU;
  __builtin_amdgcn_global_load_lds((GU*)(size_t)g, (LU*)(unsigned int)(size_t)l, 16, 0, 0);
}

// gelu_tanh via sigmoid identity: 0.5x(1+tanh(u)) = x*sigma(2u). Overflow-safe.
__device__ __forceinline__ float gelu_tanh(float x) {
  float y = 1.5957691216057308f * (x + 0.044715f * x * x * x);
  return x / (1.0f + __expf(-y));
}

// ---------------- RoPE cos/sin table: tab[s*32+d2] = {cos, sin} ----------------
__global__ __launch_bounds__(256) void rope_tab_init(const int* __restrict__ pos,
                                                     float2* __restrict__ tab) {
  int idx = blockIdx.x * 256 + threadIdx.x;  // over S*32
  int d2 = idx & 31, s = idx >> 5;
  float invf = __expf(-0.2878231366242557f * (float)d2);  // 10000^(-d2/32)
  float th = (float)pos[s] * invf;
  float sn, cs;
  __sincosf(th, &sn, &cs);
  tab[idx] = make_float2(cs, sn);
}

// ---------------- weight fp32 [K,N] -> bf16 [N,K] transpose (z = layer) ----------------
__global__ __launch_bounds__(256) void wconv(const float* __restrict__ src0,
                                             unsigned short* __restrict__ dst0,
                                             int K, int N) {
  __shared__ float t[32][33];
  const float* src = src0 + (size_t)blockIdx.z * K * N;
  unsigned short* dst = dst0 + (size_t)blockIdx.z * N * K;
  int n0 = blockIdx.x * 32, k0 = blockIdx.y * 32;
  int tid = threadIdx.x;
  int r = tid >> 3, c = (tid & 7) * 4;
  const float* s = src + (size_t)(k0 + r) * N + n0 + c;
  float4 v = *(const float4*)s;
  t[r][c] = v.x; t[r][c + 1] = v.y; t[r][c + 2] = v.z; t[r][c + 3] = v.w;
  __syncthreads();
  ushort4 o;
  o.x = f2bf(t[c + 0][r]); o.y = f2bf(t[c + 1][r]);
  o.z = f2bf(t[c + 2][r]); o.w = f2bf(t[c + 3][r]);
  *(ushort4*)(dst + (size_t)(n0 + r) * K + k0 + c) = o;
}

// ---------------- LayerNorm -> bf16 out ----------------
__global__ __launch_bounds__(256) void ln_kernel(const float* __restrict__ x,
                                                 const float* __restrict__ g,
                                                 const float* __restrict__ b,
                                                 unsigned short* __restrict__ y) {
  int row = blockIdx.x, tid = threadIdx.x;
  const float* xp = x + (size_t)row * H_;
  float4 v = *((const float4*)xp + tid);
  float s  = v.x + v.y + v.z + v.w;
  float s2 = v.x * v.x + v.y * v.y + v.z * v.z + v.w * v.w;
  #pragma unroll
  for (int o = 1; o < 64; o <<= 1) {
    s  += __shfl_xor(s, o, 64);
    s2 += __shfl_xor(s2, o, 64);
  }
  __shared__ float r1[4], r2[4];
  if ((tid & 63) == 0) { r1[tid >> 6] = s; r2[tid >> 6] = s2; }
  __syncthreads();
  s  = r1[0] + r1[1] + r1[2] + r1[3];
  s2 = r2[0] + r2[1] + r2[2] + r2[3];
  float mean = s * (1.0f / H_);
  float var  = s2 * (1.0f / H_) - mean * mean;
  float inv  = rsqrtf(var + EPS_);
  float4 gv = *((const float4*)g + tid);
  float4 bv = *((const float4*)b + tid);
  ushort4 o;
  o.x = f2bf((v.x - mean) * inv * gv.x + bv.x);
  o.y = f2bf((v.y - mean) * inv * gv.y + bv.y);
  o.z = f2bf((v.z - mean) * inv * gv.z + bv.z);
  o.w = f2bf((v.w - mean) * inv * gv.w + bv.w);
  *(ushort4*)(y + (size_t)row * H_ + tid * 4) = o;
}

// ---------------- bf16 MFMA GEMM: 128xBN tile, BK=32, 4 waves, 2-phase dbuf ----------------
// Known-good r13 schedule (stage(t+1) -> compute(t) -> __syncthreads) with BK=32:
// LDS NT=4: 32KB -> 4 blocks/CU (m97-style occupancy hides the barrier drain via
// cross-block wave overlap); NT=2: 24KB. Rows are 64B = 4 slots; swizzle:
// slot = kg ^ (fr&3), pre-swizzled source (lane&3)^(row&3) -> 2-way banks (free).
// MODE 0: bf16=A*W+bias; 1: gelu; 2: f32=resid+...; 3: qkv w/ fused RoPE (table).
template <int MODE, int NT>
__global__ __launch_bounds__(256) void gemm_mfma(
    const unsigned short* __restrict__ A, const unsigned short* __restrict__ Bt,
    const float* __restrict__ bias, const float* __restrict__ resid,
    void* __restrict__ outp, int M, int N, int K, const float2* __restrict__ rtab) {
  constexpr int BN = NT * 32;
  constexpr int ACH = 8;            // A chunks (16 rows x 64B each)
  constexpr int NCH = 8 + NT * 2;   // total chunks per K-tile
  constexpr int CPW = NCH / 4;      // chunks per wave (NT=4 -> 4, NT=2 -> 3)
  constexpr int BUFSZ = NCH * 1024; // bytes per buffer
  __shared__ __align__(16) char Ls[2 * BUFSZ];
  int tid = threadIdx.x;
  int w = tid >> 6, lane = tid & 63;
  // 2D XCD swizzle: 4x2 rectangles over (m-tiles) x (n-tiles)
  int gx = gridDim.x;
  int bid = blockIdx.y * gx + blockIdx.x;
  int xcd = bid & 7, r = bid >> 3;
  int rw = gx >> 1;
  int ry = xcd >> 1, rx = xcd & 1;
  int lm = r / rw, ln = r % rw;
  int m0 = (ry * (gridDim.y >> 2) + lm) * 128;
  int n0 = (rx * rw + ln) * BN;
  int wr = w >> 1, wc = w & 1;
  int fr = lane & 15, kg = lane >> 4;
  f32x4 acc[4][NT];
  #pragma unroll
  for (int m = 0; m < 4; m++)
    #pragma unroll
    for (int n = 0; n < NT; n++) {
      acc[m][n][0] = 0.f; acc[m][n][1] = 0.f; acc[m][n][2] = 0.f; acc[m][n][3] = 0.f;
    }
  // staging: chunk = 16 rows x 64B; lane -> row lane>>2, slot (lane&3)^(row&3)
  int srow = lane >> 2;
  int scol = ((lane & 3) ^ (srow & 3)) * 8;  // pre-swizzled global source (elems)
  const unsigned short* sbase[CPW];
  int soff[CPW];
  #pragma unroll
  for (int i = 0; i < CPW; i++) {
    int c = w * CPW + i;
    sbase[i] = (c < ACH) ? A  + (size_t)(m0 + c * 16 + srow) * K + scol
                         : Bt + (size_t)(n0 + (c - ACH) * 16 + srow) * K + scol;
    soff[i] = c * 1024;
  }
  int rsl = (fr & 3);  // read-side swizzle key
  int nk = K >> 5;

  #define STAGE_(tk, bsel)                                                     \
    {                                                                          \
      _Pragma("unroll")                                                        \
      for (int i = 0; i < CPW; i++)                                            \
        gload16(sbase[i] + (size_t)(tk) * 32, Ls + (bsel) * BUFSZ + soff[i]);  \
    }

  STAGE_(0, 0);
  __syncthreads();
  for (int t = 0; t < nk; t++) {
    int cur = t & 1;
    if (t + 1 < nk) STAGE_(t + 1, cur ^ 1);
    const char* bufc = Ls + cur * BUFSZ;
    int slot = (kg ^ rsl) << 4;
    short8_t af[4], bfv[NT];
    #pragma unroll
    for (int m = 0; m < 4; m++)
      af[m] = *(const short8_t*)(bufc + (wr * 64 + m * 16 + fr) * 64 + slot);
    #pragma unroll
    for (int n = 0; n < NT; n++)
      bfv[n] = *(const short8_t*)(bufc + ACH * 1024 + (wc * (NT * 16) + n * 16 + fr) * 64 + slot);
    #pragma unroll
    for (int m = 0; m < 4; m++)
      #pragma unroll
      for (int n = 0; n < NT; n++)
        acc[m][n] = __builtin_amdgcn_mfma_f32_16x16x32_bf16(af[m], bfv[n], acc[m][n], 0, 0, 0);
    __syncthreads();
  }
  #undef STAGE_

  if (MODE == 3) {
    int seg = n0 >> 10;  // 0=q, 1=k, 2=v
    if (seg < 2) {
      #pragma unroll
      for (int n = 0; n < 2; n++) {
        int col0 = n0 + wc * 64 + n * 16 + fr;
        int d2 = n * 16 + fr;
        float bv0 = bias[col0], bv2 = bias[col0 + 32];
        #pragma unroll
        for (int m = 0; m < 4; m++) {
          int row = m0 + wr * 64 + m * 16 + kg * 4;
          #pragma unroll
          for (int r2 = 0; r2 < 4; r2++) {
            int s = (row + r2) & (S_ - 1);
            float2 cssn = rtab[(s << 5) + d2];
            float a0 = acc[m][n][r2] + bv0;
            float a2 = acc[m][n + 2][r2] + bv2;
            size_t base = (size_t)(row + r2) * N;
            ((unsigned short*)outp)[base + col0]      = f2bf(a0 * cssn.x - a2 * cssn.y);
            ((unsigned short*)outp)[base + col0 + 32] = f2bf(a2 * cssn.x + a0 * cssn.y);
          }
        }
      }
    } else {
      #pragma unroll
      for (int n = 0; n < NT; n++) {
        int col = n0 + wc * (NT * 16) + n * 16 + fr;
        float bv = bias[col];
        #pragma unroll
        for (int m = 0; m < 4; m++) {
          int row = m0 + wr * 64 + m * 16 + kg * 4;
          #pragma unroll
          for (int r2 = 0; r2 < 4; r2++)
            ((unsigned short*)outp)[(size_t)(row + r2) * N + col] = f2bf(acc[m][n][r2] + bv);
        }
      }
    }
    return;
  }
  #pragma unroll
  for (int n = 0; n < NT; n++) {
    int col = n0 + wc * (NT * 16) + n * 16 + fr;
    float bv = bias[col];
    #pragma unroll
    for (int m = 0; m < 4; m++) {
      int row = m0 + wr * 64 + m * 16 + kg * 4;
      #pragma unroll
      for (int r2 = 0; r2 < 4; r2++) {
        float v = acc[m][n][r2] + bv;
        size_t idx = (size_t)(row + r2) * N + col;
        if (MODE == 2)      ((float*)outp)[idx] = resid[idx] + v;
        else if (MODE == 1) ((unsigned short*)outp)[idx] = f2bf(gelu_tanh(v));
        else                ((unsigned short*)outp)[idx] = f2bf(v);
      }
    }
  }
}

// ---------------- MFMA flash attention v9: QBLK=64, 4 blocks/CU, quad-balanced ----------------
__global__ __launch_bounds__(256) void attn9(const unsigned short* __restrict__ qkv,
                                             unsigned short* __restrict__ aout) {
  __shared__ __align__(16) unsigned short Ks[2][64 * 64];   // [kv][d], swizzled
  __shared__ __align__(16) unsigned short Vt[2][64 * 64];   // [d][kv], swizzled
  __shared__ __align__(16) unsigned short Ps[4][16 * 64];   // [q][kv], swizzled
  const float SCL2 = 0.18033688011112443f;  // 0.125 * log2(e)
  const float THR2 = 11.541560327111708f;   // 8 * log2(e)
  int tid = threadIdx.x;
  int w = tid >> 6, lane = tid & 63;
  int fr = lane & 15, kg = lane >> 4;
  // quad-balanced bijective remap over (qt, head, b)
  int lid = ((blockIdx.z << 4) + blockIdx.y) * 16 + blockIdx.x;  // 0..1023
  int phase = lid >> 8, s256 = lid & 255;
  int i = s256 >> 6, combo = s256 & 63;
  int qt;
  if (phase == 0)      qt = 15 - i;
  else if (phase == 1) qt = i;
  else if (phase == 2) qt = 11 - i;
  else                 qt = 4 + i;
  int head = combo & 15, b = combo >> 4;
  int q0 = qt * 64;
  const unsigned short* base = qkv + ((size_t)b * S_) * 3072 + head * 64;

  const unsigned short* qp = base + (size_t)(q0 + w * 16 + fr) * 3072 + kg * 8;
  short8_t qa0 = *(const short8_t*)qp;
  short8_t qa1 = *(const short8_t*)(qp + 32);

  f32x4 acc[4];  // O^T: [d-tile n]: lane holds d=kg*4+j, q=fr
  float mrun = -3.0e38f, lrun = 0.f;
  #pragma unroll
  for (int n = 0; n < 4; n++) {
    acc[n][0] = 0.f; acc[n][1] = 0.f; acc[n][2] = 0.f; acc[n][3] = 0.f;
  }

  int skv = lane;       // staging: kv row
  int sd0 = w * 16;     // staging: dk offset
  int qrow = q0 + w * 16 + fr;

  const unsigned short* kp0 = base + 1024 + (size_t)skv * 3072 + sd0;
  short8_t ka = *(const short8_t*)kp0;
  short8_t kb = *(const short8_t*)(kp0 + 8);
  short8_t va = *(const short8_t*)(kp0 + 1024);
  short8_t vb = *(const short8_t*)(kp0 + 1032);

  int ntiles = qt + 1;
  for (int t = 0; t < ntiles; t++) {
    int cur = t & 1;
    {
      unsigned kbyte = skv * 128 + sd0 * 2;
      unsigned ksw = (skv & 7) << 4;
      *(short8_t*)((char*)Ks[cur] + (kbyte ^ ksw)) = ka;
      *(short8_t*)((char*)Ks[cur] + ((kbyte + 16) ^ ksw)) = kb;
      #pragma unroll
      for (int j = 0; j < 8; j++) {
        int d0 = sd0 + j, d1 = sd0 + 8 + j;
        *(unsigned short*)((char*)Vt[cur] + ((d0 * 128 + skv * 2) ^ ((d0 & 7) << 4))) = (unsigned short)va[j];
        *(unsigned short*)((char*)Vt[cur] + ((d1 * 128 + skv * 2) ^ ((d1 & 7) << 4))) = (unsigned short)vb[j];
      }
    }
    if (t + 1 < ntiles) {
      const unsigned short* kp = base + 1024 + (size_t)((t + 1) * 64 + skv) * 3072 + sd0;
      ka = *(const short8_t*)kp;
      kb = *(const short8_t*)(kp + 8);
      va = *(const short8_t*)(kp + 1024);
      vb = *(const short8_t*)(kp + 1032);
    }
    __syncthreads();
    // ---- K and V fragments issued together: V latency hides under QK+softmax ----
    short8_t b0[4], b1[4], v0[4], v1[4];
    #pragma unroll
    for (int n = 0; n < 4; n++) {
      int kvrow = n * 16 + fr;
      unsigned sw = (kvrow & 7) << 4;
      b0[n] = *(const short8_t*)((char*)Ks[cur] + ((kvrow * 128 + kg * 16) ^ sw));
      b1[n] = *(const short8_t*)((char*)Ks[cur] + ((kvrow * 128 + 64 + kg * 16) ^ sw));
    }
    #pragma unroll
    for (int n = 0; n < 4; n++) {
      int d = n * 16 + fr;
      unsigned sw = (d & 7) << 4;
      v0[n] = *(const short8_t*)((char*)Vt[cur] + ((d * 128 + kg * 16) ^ sw));
      v1[n] = *(const short8_t*)((char*)Vt[cur] + ((d * 128 + 64 + kg * 16) ^ sw));
    }
    // ---- QK^T swapped: st[n]; lane: q=fr, kv=n*16+kg*4+j ----
    f32x4 st[4];
    __builtin_amdgcn_s_setprio(1);
    #pragma unroll
    for (int n = 0; n < 4; n++) {
      f32x4 z; z[0] = 0.f; z[1] = 0.f; z[2] = 0.f; z[3] = 0.f;
      z = __builtin_amdgcn_mfma_f32_16x16x32_bf16(b0[n], qa0, z, 0, 0, 0);
      z = __builtin_amdgcn_mfma_f32_16x16x32_bf16(b1[n], qa1, z, 0, 0, 0);
      st[n] = z;
    }
    __builtin_amdgcn_s_setprio(0);
    // ---- softmax (exp2 domain), defer-max, per-lane scalars ----
    bool diag = (t == qt);
    float rm = -3.0e38f;
    #pragma unroll
    for (int n = 0; n < 4; n++)
      #pragma unroll
      for (int j = 0; j < 4; j++) {
        float sv = st[n][j] * SCL2;
        if (diag && (t * 64 + n * 16 + kg * 4 + j > qrow)) sv = -1.0e30f;
        st[n][j] = sv;
        rm = fmaxf(rm, sv);
      }
    if (__any(rm > mrun + THR2)) {
      rm = fmaxf(rm, __shfl_xor(rm, 16, 64));
      rm = fmaxf(rm, __shfl_xor(rm, 32, 64));
      float mn = fmaxf(mrun, rm);
      float sc = exp2f(mrun - mn);
      mrun = mn;
      lrun *= sc;
      #pragma unroll
      for (int n = 0; n < 4; n++) {
        acc[n][0] *= sc; acc[n][1] *= sc; acc[n][2] *= sc; acc[n][3] *= sc;
      }
    }
    {
      float ls = 0.f;
      #pragma unroll
      for (int n = 0; n < 4; n++) {
        float e0 = exp2f(st[n][0] - mrun);
        float e1 = exp2f(st[n][1] - mrun);
        float e2 = exp2f(st[n][2] - mrun);
        float e3 = exp2f(st[n][3] - mrun);
        ls += (e0 + e1) + (e2 + e3);
        unsigned lo, hi;
        asm("v_cvt_pk_bf16_f32 %0, %1, %2" : "=v"(lo) : "v"(e0), "v"(e1));
        asm("v_cvt_pk_bf16_f32 %0, %1, %2" : "=v"(hi) : "v"(e2), "v"(e3));
        uint2 pk; pk.x = lo; pk.y = hi;
        *(uint2*)((char*)Ps[w] + ((fr * 128 + n * 32 + kg * 8) ^ ((fr & 7) << 4))) = pk;
      }
      lrun += ls;
    }
    asm volatile("s_waitcnt lgkmcnt(0)" ::: "memory");
    // ---- PV swapped: acc += mfma(V^T, P^T); V already in regs ----
    unsigned psw = (fr & 7) << 4;
    short8_t pa0 = *(const short8_t*)((char*)Ps[w] + ((fr * 128 + kg * 16) ^ psw));
    short8_t pa1 = *(const short8_t*)((char*)Ps[w] + ((fr * 128 + 64 + kg * 16) ^ psw));
    __builtin_amdgcn_s_setprio(1);
    #pragma unroll
    for (int n = 0; n < 4; n++) {
      acc[n] = __builtin_amdgcn_mfma_f32_16x16x32_bf16(v0[n], pa0, acc[n], 0, 0, 0);
      acc[n] = __builtin_amdgcn_mfma_f32_16x16x32_bf16(v1[n], pa1, acc[n], 0, 0, 0);
    }
    __builtin_amdgcn_s_setprio(0);
  }
  // ---- epilogue: O^T -> out; lane q=fr, d = n*16+kg*4+j ----
  {
    float ls = lrun;
    ls += __shfl_xor(ls, 16, 64);
    ls += __shfl_xor(ls, 32, 64);
    float inv = 1.0f / ls;
    size_t row = (size_t)b * S_ + q0 + w * 16 + fr;
    unsigned short* op = aout + row * H_ + head * 64 + kg * 4;
    #pragma unroll
    for (int n = 0; n < 4; n++) {
      ushort4 o;
      o.x = f2bf(acc[n][0] * inv);
      o.y = f2bf(acc[n][1] * inv);
      o.z = f2bf(acc[n][2] * inv);
      o.w = f2bf(acc[n][3] * inv);
      *(ushort4*)(op + n * 16) = o;
    }
  }
}

extern "C" void kernel_launch(void* const* d_in, const int* in_sizes, int n_in,
                              void* d_out, int out_size, void* d_ws, size_t ws_size,
                              hipStream_t stream) {
  const float* hs     = (const float*)d_in[0];
  const float* attn_w = (const float*)d_in[1];
  const float* attn_b = (const float*)d_in[2];
  const float* proj_w = (const float*)d_in[3];
  const float* proj_b = (const float*)d_in[4];
  const float* fc_w   = (const float*)d_in[5];
  const float* fc_b   = (const float*)d_in[6];
  const float* fc2_w  = (const float*)d_in[7];
  const float* fc2_b  = (const float*)d_in[8];
  const float* ln1_g  = (const float*)d_in[9];
  const float* ln1_b  = (const float*)d_in[10];
  const float* ln2_g  = (const float*)d_in[11];
  const float* ln2_b  = (const float*)d_in[12];
  const int*   pos    = (const int*)d_in[13];

  float* hres = (float*)d_out;
  const size_t rows = (size_t)B_ * S_;  // 4096

  unsigned short* wQ    = (unsigned short*)d_ws;          // [L][3072][1024]
  unsigned short* wP    = wQ  + (size_t)2 * 3072 * 1024;  // [L][1024][1024]
  unsigned short* wF1   = wP  + (size_t)2 * 1024 * 1024;  // [L][4096][1024]
  unsigned short* wF2   = wF1 + (size_t)2 * 4096 * 1024;  // [L][1024][4096]
  unsigned short* xbf   = wF2 + (size_t)2 * 1024 * 4096;  // [4096][1024]
  unsigned short* qkvbf = xbf + rows * H_;                // [4096][3072]
  unsigned short* midbf = qkvbf + rows * 3 * H_;          // [4096][4096]
  unsigned short* aoutbf= midbf + rows * MLPH_;           // [4096][1024]
  float2* rtab = (float2*)(aoutbf + rows * H_);           // [S][32] cos/sin

  rope_tab_init<<<128, 256, 0, stream>>>(pos, rtab);
  wconv<<<dim3(96, 32, 2), 256, 0, stream>>>(attn_w, wQ, 1024, 3072);
  wconv<<<dim3(32, 32, 2), 256, 0, stream>>>(proj_w, wP, 1024, 1024);
  wconv<<<dim3(128, 32, 2), 256, 0, stream>>>(fc_w, wF1, 1024, 4096);
  wconv<<<dim3(32, 128, 2), 256, 0, stream>>>(fc2_w, wF2, 4096, 1024);

  for (int l = 0; l < 2; l++) {
    const float* hin = (l == 0) ? hs : hres;  // l=0: read input directly
    ln_kernel<<<rows, 256, 0, stream>>>(hin, ln1_g + l * H_, ln1_b + l * H_, xbf);
    gemm_mfma<3, 4><<<dim3(24, 32), 256, 0, stream>>>(
        xbf, wQ + (size_t)l * 3072 * 1024, attn_b + (size_t)l * 3072, nullptr,
        qkvbf, 4096, 3072, 1024, rtab);
    attn9<<<dim3(16, 16, 4), 256, 0, stream>>>(qkvbf, aoutbf);
    gemm_mfma<2, 2><<<dim3(16, 32), 256, 0, stream>>>(
        aoutbf, wP + (size_t)l * 1024 * 1024, proj_b + (size_t)l * 1024, hin,
        hres, 4096, 1024, 1024, nullptr);
    ln_kernel<<<rows, 256, 0, stream>>>(hres, ln2_g + l * H_, ln2_b + l * H_, xbf);
    gemm_mfma<1, 4><<<dim3(32, 32), 256, 0, stream>>>(
        xbf, wF1 + (size_t)l * 4096 * 1024, fc_b + (size_t)l * 4096, nullptr,
        midbf, 4096, 4096, 1024, nullptr);
    gemm_mfma<2, 2><<<dim3(16, 32), 256, 0, stream>>>(
        midbf, wF2 + (size_t)l * 1024 * 4096, fc2_b + (size_t)l * 1024, hres,
        hres, 4096, 1024, 4096, nullptr);
  }
}

// Round 17
// 404.005 us; speedup vs baseline: 1.1637x; 1.1637x over previous
//
#include <hip/hip_runtime.h>

#define B_ 4
#define S_ 1024
#define H_ 1024
#define NH_ 16
#define DK_ 64
#define MLPH_ 4096
#define EPS_ 1e-5f

typedef __attribute__((ext_vector_type(8))) short short8_t;
typedef __attribute__((ext_vector_type(8))) unsigned short ushort8_t;
typedef __attribute__((ext_vector_type(4))) float f32x4;

__device__ __forceinline__ unsigned short f2bf(float f) {
  unsigned int u = __float_as_uint(f);
  u = u + 0x7fffu + ((u >> 16) & 1u);  // RNE
  return (unsigned short)(u >> 16);
}
__device__ __forceinline__ float bf2f(unsigned short b) {
  return __uint_as_float(((unsigned int)b) << 16);
}

__device__ __forceinline__ void gload16(const void* g, void* l) {
  typedef const __attribute__((address_space(1))) unsigned int GU;
  typedef __attribute__((address_space(3))) unsigned int LU;
  __builtin_amdgcn_global_load_lds((GU*)(size_t)g, (LU*)(unsigned int)(size_t)l, 16, 0, 0);
}

// gelu_tanh via sigmoid identity: 0.5x(1+tanh(u)) = x*sigma(2u). Overflow-safe.
__device__ __forceinline__ float gelu_tanh(float x) {
  float y = 1.5957691216057308f * (x + 0.044715f * x * x * x);
  return x / (1.0f + __expf(-y));
}

// ---------------- RoPE cos/sin table: tab[s*32+d2] = {cos, sin} ----------------
__global__ __launch_bounds__(256) void rope_tab_init(const int* __restrict__ pos,
                                                     float2* __restrict__ tab) {
  int idx = blockIdx.x * 256 + threadIdx.x;  // over S*32
  int d2 = idx & 31, s = idx >> 5;
  float invf = __expf(-0.2878231366242557f * (float)d2);  // 10000^(-d2/32)
  float th = (float)pos[s] * invf;
  float sn, cs;
  __sincosf(th, &sn, &cs);
  tab[idx] = make_float2(cs, sn);
}

// ---------------- weight fp32 [K,N] -> bf16 [N,K] transpose (z = layer) ----------------
__global__ __launch_bounds__(256) void wconv(const float* __restrict__ src0,
                                             unsigned short* __restrict__ dst0,
                                             int K, int N) {
  __shared__ float t[32][33];
  const float* src = src0 + (size_t)blockIdx.z * K * N;
  unsigned short* dst = dst0 + (size_t)blockIdx.z * N * K;
  int n0 = blockIdx.x * 32, k0 = blockIdx.y * 32;
  int tid = threadIdx.x;
  int r = tid >> 3, c = (tid & 7) * 4;
  const float* s = src + (size_t)(k0 + r) * N + n0 + c;
  float4 v = *(const float4*)s;
  t[r][c] = v.x; t[r][c + 1] = v.y; t[r][c + 2] = v.z; t[r][c + 3] = v.w;
  __syncthreads();
  ushort4 o;
  o.x = f2bf(t[c + 0][r]); o.y = f2bf(t[c + 1][r]);
  o.z = f2bf(t[c + 2][r]); o.w = f2bf(t[c + 3][r]);
  *(ushort4*)(dst + (size_t)(n0 + r) * K + k0 + c) = o;
}

// ---------------- LayerNorm -> bf16 out ----------------
__global__ __launch_bounds__(256) void ln_kernel(const float* __restrict__ x,
                                                 const float* __restrict__ g,
                                                 const float* __restrict__ b,
                                                 unsigned short* __restrict__ y) {
  int row = blockIdx.x, tid = threadIdx.x;
  const float* xp = x + (size_t)row * H_;
  float4 v = *((const float4*)xp + tid);
  float s  = v.x + v.y + v.z + v.w;
  float s2 = v.x * v.x + v.y * v.y + v.z * v.z + v.w * v.w;
  #pragma unroll
  for (int o = 1; o < 64; o <<= 1) {
    s  += __shfl_xor(s, o, 64);
    s2 += __shfl_xor(s2, o, 64);
  }
  __shared__ float r1[4], r2[4];
  if ((tid & 63) == 0) { r1[tid >> 6] = s; r2[tid >> 6] = s2; }
  __syncthreads();
  s  = r1[0] + r1[1] + r1[2] + r1[3];
  s2 = r2[0] + r2[1] + r2[2] + r2[3];
  float mean = s * (1.0f / H_);
  float var  = s2 * (1.0f / H_) - mean * mean;
  float inv  = rsqrtf(var + EPS_);
  float4 gv = *((const float4*)g + tid);
  float4 bv = *((const float4*)b + tid);
  ushort4 o;
  o.x = f2bf((v.x - mean) * inv * gv.x + bv.x);
  o.y = f2bf((v.y - mean) * inv * gv.y + bv.y);
  o.z = f2bf((v.z - mean) * inv * gv.z + bv.z);
  o.w = f2bf((v.w - mean) * inv * gv.w + bv.w);
  *(ushort4*)(y + (size_t)row * H_ + tid * 4) = o;
}

// ---------------- bf16 MFMA GEMM: 128xBN tile, BK=64, 4 waves, 2-phase dbuf ----------------
// Known-good: stage(t+1) before compute(t), one __syncthreads per tile; 2D-rect
// XCD swizzle (per-XCD L2 working set ~6.3MB); conflict-free 8-slot XOR swizzle.
// MODE 0: bf16=A*W+bias; 1: gelu; 2: f32=resid+...; 3: qkv w/ fused RoPE (table).
template <int MODE, int NT>
__global__ __launch_bounds__(256) void gemm_mfma(
    const unsigned short* __restrict__ A, const unsigned short* __restrict__ Bt,
    const float* __restrict__ bias, const float* __restrict__ resid,
    void* __restrict__ outp, int M, int N, int K, const float2* __restrict__ rtab) {
  constexpr int BN = NT * 32;
  constexpr int CB = BN / 32;  // B chunks (8 rows) per wave
  __shared__ __align__(16) unsigned short As[2][128 * 64];
  __shared__ __align__(16) unsigned short Bs[2][BN * 64];
  int tid = threadIdx.x;
  int w = tid >> 6, lane = tid & 63;
  // 2D XCD swizzle: 4x2 rectangles over (m-tiles) x (n-tiles)
  int gx = gridDim.x;
  int bid = blockIdx.y * gx + blockIdx.x;
  int xcd = bid & 7, r = bid >> 3;
  int rw = gx >> 1;
  int ry = xcd >> 1, rx = xcd & 1;
  int lm = r / rw, ln = r % rw;
  int m0 = (ry * (gridDim.y >> 2) + lm) * 128;
  int n0 = (rx * rw + ln) * BN;
  int wr = w >> 1, wc = w & 1;
  int fr = lane & 15, kg = lane >> 4;
  f32x4 acc[4][NT];
  #pragma unroll
  for (int m = 0; m < 4; m++)
    #pragma unroll
    for (int n = 0; n < NT; n++) {
      acc[m][n][0] = 0.f; acc[m][n][1] = 0.f; acc[m][n][2] = 0.f; acc[m][n][3] = 0.f;
    }
  int srow = lane >> 3;
  int scol = ((lane & 7) ^ srow) * 8;  // pre-swizzled global source
  const unsigned short* Ap = A  + (size_t)(m0 + w * 32 + srow) * K + scol;
  const unsigned short* Bp = Bt + (size_t)(n0 + w * (8 * CB) + srow) * K + scol;
  int sx = (fr & 7);  // read-side swizzle key
  int nk = K >> 6;
  // prologue: stage tile 0 -> buf 0
  {
    char* AsB = (char*)As[0] + w * 4096;
    char* BsB = (char*)Bs[0] + w * CB * 1024;
    #pragma unroll
    for (int i = 0; i < 4; i++) gload16(Ap + (size_t)i * 8 * K, AsB + i * 1024);
    #pragma unroll
    for (int i = 0; i < CB; i++) gload16(Bp + (size_t)i * 8 * K, BsB + i * 1024);
  }
  __syncthreads();
  for (int t = 0; t < nk; t++) {
    int cur = t & 1;
    if (t + 1 < nk) {
      const unsigned short* Ap2 = Ap + (size_t)(t + 1) * 64;
      const unsigned short* Bp2 = Bp + (size_t)(t + 1) * 64;
      char* AsB = (char*)As[cur ^ 1] + w * 4096;
      char* BsB = (char*)Bs[cur ^ 1] + w * CB * 1024;
      #pragma unroll
      for (int i = 0; i < 4; i++) gload16(Ap2 + (size_t)i * 8 * K, AsB + i * 1024);
      #pragma unroll
      for (int i = 0; i < CB; i++) gload16(Bp2 + (size_t)i * 8 * K, BsB + i * 1024);
    }
    #pragma unroll
    for (int kk = 0; kk < 2; kk++) {
      int slot = ((kk * 4 + kg) ^ sx) << 4;
      short8_t af[4], bfr[NT];
      #pragma unroll
      for (int m = 0; m < 4; m++)
        af[m] = *(const short8_t*)((char*)As[cur] + (wr * 64 + m * 16 + fr) * 128 + slot);
      #pragma unroll
      for (int n = 0; n < NT; n++)
        bfr[n] = *(const short8_t*)((char*)Bs[cur] + (wc * (NT * 16) + n * 16 + fr) * 128 + slot);
      #pragma unroll
      for (int m = 0; m < 4; m++)
        #pragma unroll
        for (int n = 0; n < NT; n++)
          acc[m][n] = __builtin_amdgcn_mfma_f32_16x16x32_bf16(af[m], bfr[n], acc[m][n], 0, 0, 0);
    }
    __syncthreads();
  }

  if (MODE == 3) {
    int seg = n0 >> 10;  // 0=q, 1=k, 2=v
    if (seg < 2) {
      #pragma unroll
      for (int n = 0; n < 2; n++) {
        int col0 = n0 + wc * 64 + n * 16 + fr;
        int d2 = n * 16 + fr;
        float bv0 = bias[col0], bv2 = bias[col0 + 32];
        #pragma unroll
        for (int m = 0; m < 4; m++) {
          int row = m0 + wr * 64 + m * 16 + kg * 4;
          #pragma unroll
          for (int r2 = 0; r2 < 4; r2++) {
            int s = (row + r2) & (S_ - 1);
            float2 cssn = rtab[(s << 5) + d2];
            float a0 = acc[m][n][r2] + bv0;
            float a2 = acc[m][n + 2][r2] + bv2;
            size_t base = (size_t)(row + r2) * N;
            ((unsigned short*)outp)[base + col0]      = f2bf(a0 * cssn.x - a2 * cssn.y);
            ((unsigned short*)outp)[base + col0 + 32] = f2bf(a2 * cssn.x + a0 * cssn.y);
          }
        }
      }
    } else {
      #pragma unroll
      for (int n = 0; n < NT; n++) {
        int col = n0 + wc * (NT * 16) + n * 16 + fr;
        float bv = bias[col];
        #pragma unroll
        for (int m = 0; m < 4; m++) {
          int row = m0 + wr * 64 + m * 16 + kg * 4;
          #pragma unroll
          for (int r2 = 0; r2 < 4; r2++)
            ((unsigned short*)outp)[(size_t)(row + r2) * N + col] = f2bf(acc[m][n][r2] + bv);
        }
      }
    }
    return;
  }
  #pragma unroll
  for (int n = 0; n < NT; n++) {
    int col = n0 + wc * (NT * 16) + n * 16 + fr;
    float bv = bias[col];
    #pragma unroll
    for (int m = 0; m < 4; m++) {
      int row = m0 + wr * 64 + m * 16 + kg * 4;
      #pragma unroll
      for (int r2 = 0; r2 < 4; r2++) {
        float v = acc[m][n][r2] + bv;
        size_t idx = (size_t)(row + r2) * N + col;
        if (MODE == 2)      ((float*)outp)[idx] = resid[idx] + v;
        else if (MODE == 1) ((unsigned short*)outp)[idx] = f2bf(gelu_tanh(v));
        else                ((unsigned short*)outp)[idx] = f2bf(v);
      }
    }
  }
}

// ---------------- MFMA flash attention v9: QBLK=64, 4 blocks/CU, quad-balanced ----------------
__global__ __launch_bounds__(256) void attn9(const unsigned short* __restrict__ qkv,
                                             unsigned short* __restrict__ aout) {
  __shared__ __align__(16) unsigned short Ks[2][64 * 64];   // [kv][d], swizzled
  __shared__ __align__(16) unsigned short Vt[2][64 * 64];   // [d][kv], swizzled
  __shared__ __align__(16) unsigned short Ps[4][16 * 64];   // [q][kv], swizzled
  const float SCL2 = 0.18033688011112443f;  // 0.125 * log2(e)
  const float THR2 = 11.541560327111708f;   // 8 * log2(e)
  int tid = threadIdx.x;
  int w = tid >> 6, lane = tid & 63;
  int fr = lane & 15, kg = lane >> 4;
  // quad-balanced bijective remap over (qt, head, b)
  int lid = ((blockIdx.z << 4) + blockIdx.y) * 16 + blockIdx.x;  // 0..1023
  int phase = lid >> 8, s256 = lid & 255;
  int i = s256 >> 6, combo = s256 & 63;
  int qt;
  if (phase == 0)      qt = 15 - i;
  else if (phase == 1) qt = i;
  else if (phase == 2) qt = 11 - i;
  else                 qt = 4 + i;
  int head = combo & 15, b = combo >> 4;
  int q0 = qt * 64;
  const unsigned short* base = qkv + ((size_t)b * S_) * 3072 + head * 64;

  const unsigned short* qp = base + (size_t)(q0 + w * 16 + fr) * 3072 + kg * 8;
  short8_t qa0 = *(const short8_t*)qp;
  short8_t qa1 = *(const short8_t*)(qp + 32);

  f32x4 acc[4];  // O^T: [d-tile n]: lane holds d=kg*4+j, q=fr
  float mrun = -3.0e38f, lrun = 0.f;
  #pragma unroll
  for (int n = 0; n < 4; n++) {
    acc[n][0] = 0.f; acc[n][1] = 0.f; acc[n][2] = 0.f; acc[n][3] = 0.f;
  }

  int skv = lane;       // staging: kv row
  int sd0 = w * 16;     // staging: dk offset
  int qrow = q0 + w * 16 + fr;

  const unsigned short* kp0 = base + 1024 + (size_t)skv * 3072 + sd0;
  short8_t ka = *(const short8_t*)kp0;
  short8_t kb = *(const short8_t*)(kp0 + 8);
  short8_t va = *(const short8_t*)(kp0 + 1024);
  short8_t vb = *(const short8_t*)(kp0 + 1032);

  int ntiles = qt + 1;
  for (int t = 0; t < ntiles; t++) {
    int cur = t & 1;
    {
      unsigned kbyte = skv * 128 + sd0 * 2;
      unsigned ksw = (skv & 7) << 4;
      *(short8_t*)((char*)Ks[cur] + (kbyte ^ ksw)) = ka;
      *(short8_t*)((char*)Ks[cur] + ((kbyte + 16) ^ ksw)) = kb;
      #pragma unroll
      for (int j = 0; j < 8; j++) {
        int d0 = sd0 + j, d1 = sd0 + 8 + j;
        *(unsigned short*)((char*)Vt[cur] + ((d0 * 128 + skv * 2) ^ ((d0 & 7) << 4))) = (unsigned short)va[j];
        *(unsigned short*)((char*)Vt[cur] + ((d1 * 128 + skv * 2) ^ ((d1 & 7) << 4))) = (unsigned short)vb[j];
      }
    }
    if (t + 1 < ntiles) {
      const unsigned short* kp = base + 1024 + (size_t)((t + 1) * 64 + skv) * 3072 + sd0;
      ka = *(const short8_t*)kp;
      kb = *(const short8_t*)(kp + 8);
      va = *(const short8_t*)(kp + 1024);
      vb = *(const short8_t*)(kp + 1032);
    }
    __syncthreads();
    // ---- K and V fragments issued together: V latency hides under QK+softmax ----
    short8_t b0[4], b1[4], v0[4], v1[4];
    #pragma unroll
    for (int n = 0; n < 4; n++) {
      int kvrow = n * 16 + fr;
      unsigned sw = (kvrow & 7) << 4;
      b0[n] = *(const short8_t*)((char*)Ks[cur] + ((kvrow * 128 + kg * 16) ^ sw));
      b1[n] = *(const short8_t*)((char*)Ks[cur] + ((kvrow * 128 + 64 + kg * 16) ^ sw));
    }
    #pragma unroll
    for (int n = 0; n < 4; n++) {
      int d = n * 16 + fr;
      unsigned sw = (d & 7) << 4;
      v0[n] = *(const short8_t*)((char*)Vt[cur] + ((d * 128 + kg * 16) ^ sw));
      v1[n] = *(const short8_t*)((char*)Vt[cur] + ((d * 128 + 64 + kg * 16) ^ sw));
    }
    // ---- QK^T swapped: st[n]; lane: q=fr, kv=n*16+kg*4+j ----
    f32x4 st[4];
    __builtin_amdgcn_s_setprio(1);
    #pragma unroll
    for (int n = 0; n < 4; n++) {
      f32x4 z; z[0] = 0.f; z[1] = 0.f; z[2] = 0.f; z[3] = 0.f;
      z = __builtin_amdgcn_mfma_f32_16x16x32_bf16(b0[n], qa0, z, 0, 0, 0);
      z = __builtin_amdgcn_mfma_f32_16x16x32_bf16(b1[n], qa1, z, 0, 0, 0);
      st[n] = z;
    }
    __builtin_amdgcn_s_setprio(0);
    // ---- softmax (exp2 domain), defer-max, per-lane scalars ----
    bool diag = (t == qt);
    float rm = -3.0e38f;
    #pragma unroll
    for (int n = 0; n < 4; n++)
      #pragma unroll
      for (int j = 0; j < 4; j++) {
        float sv = st[n][j] * SCL2;
        if (diag && (t * 64 + n * 16 + kg * 4 + j > qrow)) sv = -1.0e30f;
        st[n][j] = sv;
        rm = fmaxf(rm, sv);
      }
    if (__any(rm > mrun + THR2)) {
      rm = fmaxf(rm, __shfl_xor(rm, 16, 64));
      rm = fmaxf(rm, __shfl_xor(rm, 32, 64));
      float mn = fmaxf(mrun, rm);
      float sc = exp2f(mrun - mn);
      mrun = mn;
      lrun *= sc;
      #pragma unroll
      for (int n = 0; n < 4; n++) {
        acc[n][0] *= sc; acc[n][1] *= sc; acc[n][2] *= sc; acc[n][3] *= sc;
      }
    }
    {
      float ls = 0.f;
      #pragma unroll
      for (int n = 0; n < 4; n++) {
        float e0 = exp2f(st[n][0] - mrun);
        float e1 = exp2f(st[n][1] - mrun);
        float e2 = exp2f(st[n][2] - mrun);
        float e3 = exp2f(st[n][3] - mrun);
        ls += (e0 + e1) + (e2 + e3);
        unsigned lo, hi;
        asm("v_cvt_pk_bf16_f32 %0, %1, %2" : "=v"(lo) : "v"(e0), "v"(e1));
        asm("v_cvt_pk_bf16_f32 %0, %1, %2" : "=v"(hi) : "v"(e2), "v"(e3));
        uint2 pk; pk.x = lo; pk.y = hi;
        *(uint2*)((char*)Ps[w] + ((fr * 128 + n * 32 + kg * 8) ^ ((fr & 7) << 4))) = pk;
      }
      lrun += ls;
    }
    asm volatile("s_waitcnt lgkmcnt(0)" ::: "memory");
    // ---- PV swapped: acc += mfma(V^T, P^T); V already in regs ----
    unsigned psw = (fr & 7) << 4;
    short8_t pa0 = *(const short8_t*)((char*)Ps[w] + ((fr * 128 + kg * 16) ^ psw));
    short8_t pa1 = *(const short8_t*)((char*)Ps[w] + ((fr * 128 + 64 + kg * 16) ^ psw));
    __builtin_amdgcn_s_setprio(1);
    #pragma unroll
    for (int n = 0; n < 4; n++) {
      acc[n] = __builtin_amdgcn_mfma_f32_16x16x32_bf16(v0[n], pa0, acc[n], 0, 0, 0);
      acc[n] = __builtin_amdgcn_mfma_f32_16x16x32_bf16(v1[n], pa1, acc[n], 0, 0, 0);
    }
    __builtin_amdgcn_s_setprio(0);
  }
  // ---- epilogue: O^T -> out; lane q=fr, d = n*16+kg*4+j ----
  {
    float ls = lrun;
    ls += __shfl_xor(ls, 16, 64);
    ls += __shfl_xor(ls, 32, 64);
    float inv = 1.0f / ls;
    size_t row = (size_t)b * S_ + q0 + w * 16 + fr;
    unsigned short* op = aout + row * H_ + head * 64 + kg * 4;
    #pragma unroll
    for (int n = 0; n < 4; n++) {
      ushort4 o;
      o.x = f2bf(acc[n][0] * inv);
      o.y = f2bf(acc[n][1] * inv);
      o.z = f2bf(acc[n][2] * inv);
      o.w = f2bf(acc[n][3] * inv);
      *(ushort4*)(op + n * 16) = o;
    }
  }
}

extern "C" void kernel_launch(void* const* d_in, const int* in_sizes, int n_in,
                              void* d_out, int out_size, void* d_ws, size_t ws_size,
                              hipStream_t stream) {
  const float* hs     = (const float*)d_in[0];
  const float* attn_w = (const float*)d_in[1];
  const float* attn_b = (const float*)d_in[2];
  const float* proj_w = (const float*)d_in[3];
  const float* proj_b = (const float*)d_in[4];
  const float* fc_w   = (const float*)d_in[5];
  const float* fc_b   = (const float*)d_in[6];
  const float* fc2_w  = (const float*)d_in[7];
  const float* fc2_b  = (const float*)d_in[8];
  const float* ln1_g  = (const float*)d_in[9];
  const float* ln1_b  = (const float*)d_in[10];
  const float* ln2_g  = (const float*)d_in[11];
  const float* ln2_b  = (const float*)d_in[12];
  const int*   pos    = (const int*)d_in[13];

  float* hres = (float*)d_out;
  const size_t rows = (size_t)B_ * S_;  // 4096

  unsigned short* wQ    = (unsigned short*)d_ws;          // [L][3072][1024]
  unsigned short* wP    = wQ  + (size_t)2 * 3072 * 1024;  // [L][1024][1024]
  unsigned short* wF1   = wP  + (size_t)2 * 1024 * 1024;  // [L][4096][1024]
  unsigned short* wF2   = wF1 + (size_t)2 * 4096 * 1024;  // [L][1024][4096]
  unsigned short* xbf   = wF2 + (size_t)2 * 1024 * 4096;  // [4096][1024]
  unsigned short* qkvbf = xbf + rows * H_;                // [4096][3072]
  unsigned short* midbf = qkvbf + rows * 3 * H_;          // [4096][4096]
  unsigned short* aoutbf= midbf + rows * MLPH_;           // [4096][1024]
  float2* rtab = (float2*)(aoutbf + rows * H_);           // [S][32] cos/sin

  rope_tab_init<<<128, 256, 0, stream>>>(pos, rtab);
  wconv<<<dim3(96, 32, 2), 256, 0, stream>>>(attn_w, wQ, 1024, 3072);
  wconv<<<dim3(32, 32, 2), 256, 0, stream>>>(proj_w, wP, 1024, 1024);
  wconv<<<dim3(128, 32, 2), 256, 0, stream>>>(fc_w, wF1, 1024, 4096);
  wconv<<<dim3(32, 128, 2), 256, 0, stream>>>(fc2_w, wF2, 4096, 1024);

  for (int l = 0; l < 2; l++) {
    const float* hin = (l == 0) ? hs : hres;  // l=0: read input directly
    ln_kernel<<<rows, 256, 0, stream>>>(hin, ln1_g + l * H_, ln1_b + l * H_, xbf);
    gemm_mfma<3, 4><<<dim3(24, 32), 256, 0, stream>>>(
        xbf, wQ + (size_t)l * 3072 * 1024, attn_b + (size_t)l * 3072, nullptr,
        qkvbf, 4096, 3072, 1024, rtab);
    attn9<<<dim3(16, 16, 4), 256, 0, stream>>>(qkvbf, aoutbf);
    gemm_mfma<2, 2><<<dim3(16, 32), 256, 0, stream>>>(
        aoutbf, wP + (size_t)l * 1024 * 1024, proj_b + (size_t)l * 1024, hin,
        hres, 4096, 1024, 1024, nullptr);
    ln_kernel<<<rows, 256, 0, stream>>>(hres, ln2_g + l * H_, ln2_b + l * H_, xbf);
    gemm_mfma<1, 4><<<dim3(32, 32), 256, 0, stream>>>(
        xbf, wF1 + (size_t)l * 4096 * 1024, fc_b + (size_t)l * 4096, nullptr,
        midbf, 4096, 4096, 1024, nullptr);
    gemm_mfma<2, 2><<<dim3(16, 32), 256, 0, stream>>>(
        midbf, wF2 + (size_t)l * 1024 * 4096, fc2_b + (size_t)l * 1024, hres,
        hres, 4096, 1024, 4096, nullptr);
  }
}

// Round 18
// 400.225 us; speedup vs baseline: 1.1747x; 1.0094x over previous
//
#include <hip/hip_runtime.h>

#define B_ 4
#define S_ 1024
#define H_ 1024
#define NH_ 16
#define DK_ 64
#define MLPH_ 4096
#define EPS_ 1e-5f

typedef __attribute__((ext_vector_type(8))) short short8_t;
typedef __attribute__((ext_vector_type(8))) unsigned short ushort8_t;
typedef __attribute__((ext_vector_type(4))) float f32x4;

__device__ __forceinline__ unsigned short f2bf(float f) {
  unsigned int u = __float_as_uint(f);
  u = u + 0x7fffu + ((u >> 16) & 1u);  // RNE
  return (unsigned short)(u >> 16);
}
__device__ __forceinline__ float bf2f(unsigned short b) {
  return __uint_as_float(((unsigned int)b) << 16);
}

__device__ __forceinline__ void gload16(const void* g, void* l) {
  typedef const __attribute__((address_space(1))) unsigned int GU;
  typedef __attribute__((address_space(3))) unsigned int LU;
  __builtin_amdgcn_global_load_lds((GU*)(size_t)g, (LU*)(unsigned int)(size_t)l, 16, 0, 0);
}

// gelu_tanh via sigmoid identity: 0.5x(1+tanh(u)) = x*sigma(2u). Overflow-safe.
__device__ __forceinline__ float gelu_tanh(float x) {
  float y = 1.5957691216057308f * (x + 0.044715f * x * x * x);
  return x / (1.0f + __expf(-y));
}

// ---------------- RoPE cos/sin table: tab[s*32+d2] = {cos, sin} ----------------
__global__ __launch_bounds__(256) void rope_tab_init(const int* __restrict__ pos,
                                                     float2* __restrict__ tab) {
  int idx = blockIdx.x * 256 + threadIdx.x;  // over S*32
  int d2 = idx & 31, s = idx >> 5;
  float invf = __expf(-0.2878231366242557f * (float)d2);  // 10000^(-d2/32)
  float th = (float)pos[s] * invf;
  float sn, cs;
  __sincosf(th, &sn, &cs);
  tab[idx] = make_float2(cs, sn);
}

// ---------------- merged weight convert: all 4 weights x 2 layers, one launch ----
// fp32 [K,N] -> bf16 [N,K], 32x32 tiles. Tile ranges (x2 layers):
//   attn 96x32=3072 -> 6144 | proj 32x32=1024 -> 2048 | fc1 128x32=4096 -> 8192
//   fc2 32x128=4096 -> 8192 | total 24576 blocks.
__global__ __launch_bounds__(256) void wconv_all(
    const float* __restrict__ s0, const float* __restrict__ s1,
    const float* __restrict__ s2, const float* __restrict__ s3,
    unsigned short* __restrict__ d0, unsigned short* __restrict__ d1,
    unsigned short* __restrict__ d2, unsigned short* __restrict__ d3) {
  __shared__ float t[32][33];
  int bid = blockIdx.x;
  const float* src; unsigned short* dst; int K, N, local;
  if (bid < 6144)        { src = s0; dst = d0; K = 1024; N = 3072; local = bid; }
  else if (bid < 8192)   { src = s1; dst = d1; K = 1024; N = 1024; local = bid - 6144; }
  else if (bid < 16384)  { src = s2; dst = d2; K = 1024; N = 4096; local = bid - 8192; }
  else                   { src = s3; dst = d3; K = 4096; N = 1024; local = bid - 16384; }
  int tiles = (N >> 5) * (K >> 5);
  int layer = (local >= tiles) ? 1 : 0;
  int tl = local - layer * tiles;
  src += (size_t)layer * K * N;
  dst += (size_t)layer * N * K;
  int n0 = (tl % (N >> 5)) * 32, k0 = (tl / (N >> 5)) * 32;
  int tid = threadIdx.x;
  int r = tid >> 3, c = (tid & 7) * 4;
  const float* s = src + (size_t)(k0 + r) * N + n0 + c;
  float4 v = *(const float4*)s;
  t[r][c] = v.x; t[r][c + 1] = v.y; t[r][c + 2] = v.z; t[r][c + 3] = v.w;
  __syncthreads();
  ushort4 o;
  o.x = f2bf(t[c + 0][r]); o.y = f2bf(t[c + 1][r]);
  o.z = f2bf(t[c + 2][r]); o.w = f2bf(t[c + 3][r]);
  *(ushort4*)(dst + (size_t)(n0 + r) * K + k0 + c) = o;
}

// ---------------- LayerNorm -> bf16 out ----------------
__global__ __launch_bounds__(256) void ln_kernel(const float* __restrict__ x,
                                                 const float* __restrict__ g,
                                                 const float* __restrict__ b,
                                                 unsigned short* __restrict__ y) {
  int row = blockIdx.x, tid = threadIdx.x;
  const float* xp = x + (size_t)row * H_;
  float4 v = *((const float4*)xp + tid);
  float s  = v.x + v.y + v.z + v.w;
  float s2 = v.x * v.x + v.y * v.y + v.z * v.z + v.w * v.w;
  #pragma unroll
  for (int o = 1; o < 64; o <<= 1) {
    s  += __shfl_xor(s, o, 64);
    s2 += __shfl_xor(s2, o, 64);
  }
  __shared__ float r1[4], r2[4];
  if ((tid & 63) == 0) { r1[tid >> 6] = s; r2[tid >> 6] = s2; }
  __syncthreads();
  s  = r1[0] + r1[1] + r1[2] + r1[3];
  s2 = r2[0] + r2[1] + r2[2] + r2[3];
  float mean = s * (1.0f / H_);
  float var  = s2 * (1.0f / H_) - mean * mean;
  float inv  = rsqrtf(var + EPS_);
  float4 gv = *((const float4*)g + tid);
  float4 bv = *((const float4*)b + tid);
  ushort4 o;
  o.x = f2bf((v.x - mean) * inv * gv.x + bv.x);
  o.y = f2bf((v.y - mean) * inv * gv.y + bv.y);
  o.z = f2bf((v.z - mean) * inv * gv.z + bv.z);
  o.w = f2bf((v.w - mean) * inv * gv.w + bv.w);
  *(ushort4*)(y + (size_t)row * H_ + tid * 4) = o;
}

// ---------------- bf16 MFMA GEMM: 128xBN tile, BK=64, 4 waves, 2-phase dbuf ----------------
// Known-good: stage(t+1) before compute(t), one __syncthreads per tile; 2D-rect
// XCD swizzle (per-XCD L2 working set ~6.3MB); conflict-free 8-slot XOR swizzle.
// MODE 0: bf16=A*W+bias; 1: gelu; 2: f32=resid+...; 3: qkv w/ fused RoPE (table).
template <int MODE, int NT>
__global__ __launch_bounds__(256) void gemm_mfma(
    const unsigned short* __restrict__ A, const unsigned short* __restrict__ Bt,
    const float* __restrict__ bias, const float* __restrict__ resid,
    void* __restrict__ outp, int M, int N, int K, const float2* __restrict__ rtab) {
  constexpr int BN = NT * 32;
  constexpr int CB = BN / 32;  // B chunks (8 rows) per wave
  __shared__ __align__(16) unsigned short As[2][128 * 64];
  __shared__ __align__(16) unsigned short Bs[2][BN * 64];
  int tid = threadIdx.x;
  int w = tid >> 6, lane = tid & 63;
  // 2D XCD swizzle: 4x2 rectangles over (m-tiles) x (n-tiles)
  int gx = gridDim.x;
  int bid = blockIdx.y * gx + blockIdx.x;
  int xcd = bid & 7, r = bid >> 3;
  int rw = gx >> 1;
  int ry = xcd >> 1, rx = xcd & 1;
  int lm = r / rw, ln = r % rw;
  int m0 = (ry * (gridDim.y >> 2) + lm) * 128;
  int n0 = (rx * rw + ln) * BN;
  int wr = w >> 1, wc = w & 1;
  int fr = lane & 15, kg = lane >> 4;
  f32x4 acc[4][NT];
  #pragma unroll
  for (int m = 0; m < 4; m++)
    #pragma unroll
    for (int n = 0; n < NT; n++) {
      acc[m][n][0] = 0.f; acc[m][n][1] = 0.f; acc[m][n][2] = 0.f; acc[m][n][3] = 0.f;
    }
  int srow = lane >> 3;
  int scol = ((lane & 7) ^ srow) * 8;  // pre-swizzled global source
  const unsigned short* Ap = A  + (size_t)(m0 + w * 32 + srow) * K + scol;
  const unsigned short* Bp = Bt + (size_t)(n0 + w * (8 * CB) + srow) * K + scol;
  int sx = (fr & 7);  // read-side swizzle key
  int nk = K >> 6;
  // prologue: stage tile 0 -> buf 0
  {
    char* AsB = (char*)As[0] + w * 4096;
    char* BsB = (char*)Bs[0] + w * CB * 1024;
    #pragma unroll
    for (int i = 0; i < 4; i++) gload16(Ap + (size_t)i * 8 * K, AsB + i * 1024);
    #pragma unroll
    for (int i = 0; i < CB; i++) gload16(Bp + (size_t)i * 8 * K, BsB + i * 1024);
  }
  __syncthreads();
  for (int t = 0; t < nk; t++) {
    int cur = t & 1;
    if (t + 1 < nk) {
      const unsigned short* Ap2 = Ap + (size_t)(t + 1) * 64;
      const unsigned short* Bp2 = Bp + (size_t)(t + 1) * 64;
      char* AsB = (char*)As[cur ^ 1] + w * 4096;
      char* BsB = (char*)Bs[cur ^ 1] + w * CB * 1024;
      #pragma unroll
      for (int i = 0; i < 4; i++) gload16(Ap2 + (size_t)i * 8 * K, AsB + i * 1024);
      #pragma unroll
      for (int i = 0; i < CB; i++) gload16(Bp2 + (size_t)i * 8 * K, BsB + i * 1024);
    }
    #pragma unroll
    for (int kk = 0; kk < 2; kk++) {
      int slot = ((kk * 4 + kg) ^ sx) << 4;
      short8_t af[4], bfr[NT];
      #pragma unroll
      for (int m = 0; m < 4; m++)
        af[m] = *(const short8_t*)((char*)As[cur] + (wr * 64 + m * 16 + fr) * 128 + slot);
      #pragma unroll
      for (int n = 0; n < NT; n++)
        bfr[n] = *(const short8_t*)((char*)Bs[cur] + (wc * (NT * 16) + n * 16 + fr) * 128 + slot);
      #pragma unroll
      for (int m = 0; m < 4; m++)
        #pragma unroll
        for (int n = 0; n < NT; n++)
          acc[m][n] = __builtin_amdgcn_mfma_f32_16x16x32_bf16(af[m], bfr[n], acc[m][n], 0, 0, 0);
    }
    __syncthreads();
  }

  if (MODE == 3) {
    int seg = n0 >> 10;  // 0=q, 1=k, 2=v
    if (seg < 2) {
      #pragma unroll
      for (int n = 0; n < 2; n++) {
        int col0 = n0 + wc * 64 + n * 16 + fr;
        int d2 = n * 16 + fr;
        float bv0 = bias[col0], bv2 = bias[col0 + 32];
        #pragma unroll
        for (int m = 0; m < 4; m++) {
          int row = m0 + wr * 64 + m * 16 + kg * 4;
          #pragma unroll
          for (int r2 = 0; r2 < 4; r2++) {
            int s = (row + r2) & (S_ - 1);
            float2 cssn = rtab[(s << 5) + d2];
            float a0 = acc[m][n][r2] + bv0;
            float a2 = acc[m][n + 2][r2] + bv2;
            size_t base = (size_t)(row + r2) * N;
            ((unsigned short*)outp)[base + col0]      = f2bf(a0 * cssn.x - a2 * cssn.y);
            ((unsigned short*)outp)[base + col0 + 32] = f2bf(a2 * cssn.x + a0 * cssn.y);
          }
        }
      }
    } else {
      #pragma unroll
      for (int n = 0; n < NT; n++) {
        int col = n0 + wc * (NT * 16) + n * 16 + fr;
        float bv = bias[col];
        #pragma unroll
        for (int m = 0; m < 4; m++) {
          int row = m0 + wr * 64 + m * 16 + kg * 4;
          #pragma unroll
          for (int r2 = 0; r2 < 4; r2++)
            ((unsigned short*)outp)[(size_t)(row + r2) * N + col] = f2bf(acc[m][n][r2] + bv);
        }
      }
    }
    return;
  }
  #pragma unroll
  for (int n = 0; n < NT; n++) {
    int col = n0 + wc * (NT * 16) + n * 16 + fr;
    float bv = bias[col];
    #pragma unroll
    for (int m = 0; m < 4; m++) {
      int row = m0 + wr * 64 + m * 16 + kg * 4;
      #pragma unroll
      for (int r2 = 0; r2 < 4; r2++) {
        float v = acc[m][n][r2] + bv;
        size_t idx = (size_t)(row + r2) * N + col;
        if (MODE == 2)      ((float*)outp)[idx] = resid[idx] + v;
        else if (MODE == 1) ((unsigned short*)outp)[idx] = f2bf(gelu_tanh(v));
        else                ((unsigned short*)outp)[idx] = f2bf(v);
      }
    }
  }
}

// ---------------- MFMA flash attention v9: QBLK=64, 4 blocks/CU, quad-balanced ----------------
__global__ __launch_bounds__(256) void attn9(const unsigned short* __restrict__ qkv,
                                             unsigned short* __restrict__ aout) {
  __shared__ __align__(16) unsigned short Ks[2][64 * 64];   // [kv][d], swizzled
  __shared__ __align__(16) unsigned short Vt[2][64 * 64];   // [d][kv], swizzled
  __shared__ __align__(16) unsigned short Ps[4][16 * 64];   // [q][kv], swizzled
  const float SCL2 = 0.18033688011112443f;  // 0.125 * log2(e)
  const float THR2 = 11.541560327111708f;   // 8 * log2(e)
  int tid = threadIdx.x;
  int w = tid >> 6, lane = tid & 63;
  int fr = lane & 15, kg = lane >> 4;
  // quad-balanced bijective remap over (qt, head, b)
  int lid = ((blockIdx.z << 4) + blockIdx.y) * 16 + blockIdx.x;  // 0..1023
  int phase = lid >> 8, s256 = lid & 255;
  int i = s256 >> 6, combo = s256 & 63;
  int qt;
  if (phase == 0)      qt = 15 - i;
  else if (phase == 1) qt = i;
  else if (phase == 2) qt = 11 - i;
  else                 qt = 4 + i;
  int head = combo & 15, b = combo >> 4;
  int q0 = qt * 64;
  const unsigned short* base = qkv + ((size_t)b * S_) * 3072 + head * 64;

  const unsigned short* qp = base + (size_t)(q0 + w * 16 + fr) * 3072 + kg * 8;
  short8_t qa0 = *(const short8_t*)qp;
  short8_t qa1 = *(const short8_t*)(qp + 32);

  f32x4 acc[4];  // O^T: [d-tile n]: lane holds d=kg*4+j, q=fr
  float mrun = -3.0e38f, lrun = 0.f;
  #pragma unroll
  for (int n = 0; n < 4; n++) {
    acc[n][0] = 0.f; acc[n][1] = 0.f; acc[n][2] = 0.f; acc[n][3] = 0.f;
  }

  int skv = lane;       // staging: kv row
  int sd0 = w * 16;     // staging: dk offset
  int qrow = q0 + w * 16 + fr;

  const unsigned short* kp0 = base + 1024 + (size_t)skv * 3072 + sd0;
  short8_t ka = *(const short8_t*)kp0;
  short8_t kb = *(const short8_t*)(kp0 + 8);
  short8_t va = *(const short8_t*)(kp0 + 1024);
  short8_t vb = *(const short8_t*)(kp0 + 1032);

  int ntiles = qt + 1;
  for (int t = 0; t < ntiles; t++) {
    int cur = t & 1;
    {
      unsigned kbyte = skv * 128 + sd0 * 2;
      unsigned ksw = (skv & 7) << 4;
      *(short8_t*)((char*)Ks[cur] + (kbyte ^ ksw)) = ka;
      *(short8_t*)((char*)Ks[cur] + ((kbyte + 16) ^ ksw)) = kb;
      #pragma unroll
      for (int j = 0; j < 8; j++) {
        int d0 = sd0 + j, d1 = sd0 + 8 + j;
        *(unsigned short*)((char*)Vt[cur] + ((d0 * 128 + skv * 2) ^ ((d0 & 7) << 4))) = (unsigned short)va[j];
        *(unsigned short*)((char*)Vt[cur] + ((d1 * 128 + skv * 2) ^ ((d1 & 7) << 4))) = (unsigned short)vb[j];
      }
    }
    if (t + 1 < ntiles) {
      const unsigned short* kp = base + 1024 + (size_t)((t + 1) * 64 + skv) * 3072 + sd0;
      ka = *(const short8_t*)kp;
      kb = *(const short8_t*)(kp + 8);
      va = *(const short8_t*)(kp + 1024);
      vb = *(const short8_t*)(kp + 1032);
    }
    __syncthreads();
    // ---- K and V fragments issued together: V latency hides under QK+softmax ----
    short8_t b0[4], b1[4], v0[4], v1[4];
    #pragma unroll
    for (int n = 0; n < 4; n++) {
      int kvrow = n * 16 + fr;
      unsigned sw = (kvrow & 7) << 4;
      b0[n] = *(const short8_t*)((char*)Ks[cur] + ((kvrow * 128 + kg * 16) ^ sw));
      b1[n] = *(const short8_t*)((char*)Ks[cur] + ((kvrow * 128 + 64 + kg * 16) ^ sw));
    }
    #pragma unroll
    for (int n = 0; n < 4; n++) {
      int d = n * 16 + fr;
      unsigned sw = (d & 7) << 4;
      v0[n] = *(const short8_t*)((char*)Vt[cur] + ((d * 128 + kg * 16) ^ sw));
      v1[n] = *(const short8_t*)((char*)Vt[cur] + ((d * 128 + 64 + kg * 16) ^ sw));
    }
    // ---- QK^T swapped: st[n]; lane: q=fr, kv=n*16+kg*4+j ----
    f32x4 st[4];
    __builtin_amdgcn_s_setprio(1);
    #pragma unroll
    for (int n = 0; n < 4; n++) {
      f32x4 z; z[0] = 0.f; z[1] = 0.f; z[2] = 0.f; z[3] = 0.f;
      z = __builtin_amdgcn_mfma_f32_16x16x32_bf16(b0[n], qa0, z, 0, 0, 0);
      z = __builtin_amdgcn_mfma_f32_16x16x32_bf16(b1[n], qa1, z, 0, 0, 0);
      st[n] = z;
    }
    __builtin_amdgcn_s_setprio(0);
    // ---- softmax (exp2 domain), defer-max, per-lane scalars ----
    bool diag = (t == qt);
    float rm = -3.0e38f;
    #pragma unroll
    for (int n = 0; n < 4; n++)
      #pragma unroll
      for (int j = 0; j < 4; j++) {
        float sv = st[n][j] * SCL2;
        if (diag && (t * 64 + n * 16 + kg * 4 + j > qrow)) sv = -1.0e30f;
        st[n][j] = sv;
        rm = fmaxf(rm, sv);
      }
    if (__any(rm > mrun + THR2)) {
      rm = fmaxf(rm, __shfl_xor(rm, 16, 64));
      rm = fmaxf(rm, __shfl_xor(rm, 32, 64));
      float mn = fmaxf(mrun, rm);
      float sc = exp2f(mrun - mn);
      mrun = mn;
      lrun *= sc;
      #pragma unroll
      for (int n = 0; n < 4; n++) {
        acc[n][0] *= sc; acc[n][1] *= sc; acc[n][2] *= sc; acc[n][3] *= sc;
      }
    }
    {
      float ls = 0.f;
      #pragma unroll
      for (int n = 0; n < 4; n++) {
        float e0 = exp2f(st[n][0] - mrun);
        float e1 = exp2f(st[n][1] - mrun);
        float e2 = exp2f(st[n][2] - mrun);
        float e3 = exp2f(st[n][3] - mrun);
        ls += (e0 + e1) + (e2 + e3);
        unsigned lo, hi;
        asm("v_cvt_pk_bf16_f32 %0, %1, %2" : "=v"(lo) : "v"(e0), "v"(e1));
        asm("v_cvt_pk_bf16_f32 %0, %1, %2" : "=v"(hi) : "v"(e2), "v"(e3));
        uint2 pk; pk.x = lo; pk.y = hi;
        *(uint2*)((char*)Ps[w] + ((fr * 128 + n * 32 + kg * 8) ^ ((fr & 7) << 4))) = pk;
      }
      lrun += ls;
    }
    asm volatile("s_waitcnt lgkmcnt(0)" ::: "memory");
    // ---- PV swapped: acc += mfma(V^T, P^T); V already in regs ----
    unsigned psw = (fr & 7) << 4;
    short8_t pa0 = *(const short8_t*)((char*)Ps[w] + ((fr * 128 + kg * 16) ^ psw));
    short8_t pa1 = *(const short8_t*)((char*)Ps[w] + ((fr * 128 + 64 + kg * 16) ^ psw));
    __builtin_amdgcn_s_setprio(1);
    #pragma unroll
    for (int n = 0; n < 4; n++) {
      acc[n] = __builtin_amdgcn_mfma_f32_16x16x32_bf16(v0[n], pa0, acc[n], 0, 0, 0);
      acc[n] = __builtin_amdgcn_mfma_f32_16x16x32_bf16(v1[n], pa1, acc[n], 0, 0, 0);
    }
    __builtin_amdgcn_s_setprio(0);
  }
  // ---- epilogue: O^T -> out; lane q=fr, d = n*16+kg*4+j ----
  {
    float ls = lrun;
    ls += __shfl_xor(ls, 16, 64);
    ls += __shfl_xor(ls, 32, 64);
    float inv = 1.0f / ls;
    size_t row = (size_t)b * S_ + q0 + w * 16 + fr;
    unsigned short* op = aout + row * H_ + head * 64 + kg * 4;
    #pragma unroll
    for (int n = 0; n < 4; n++) {
      ushort4 o;
      o.x = f2bf(acc[n][0] * inv);
      o.y = f2bf(acc[n][1] * inv);
      o.z = f2bf(acc[n][2] * inv);
      o.w = f2bf(acc[n][3] * inv);
      *(ushort4*)(op + n * 16) = o;
    }
  }
}

extern "C" void kernel_launch(void* const* d_in, const int* in_sizes, int n_in,
                              void* d_out, int out_size, void* d_ws, size_t ws_size,
                              hipStream_t stream) {
  const float* hs     = (const float*)d_in[0];
  const float* attn_w = (const float*)d_in[1];
  const float* attn_b = (const float*)d_in[2];
  const float* proj_w = (const float*)d_in[3];
  const float* proj_b = (const float*)d_in[4];
  const float* fc_w   = (const float*)d_in[5];
  const float* fc_b   = (const float*)d_in[6];
  const float* fc2_w  = (const float*)d_in[7];
  const float* fc2_b  = (const float*)d_in[8];
  const float* ln1_g  = (const float*)d_in[9];
  const float* ln1_b  = (const float*)d_in[10];
  const float* ln2_g  = (const float*)d_in[11];
  const float* ln2_b  = (const float*)d_in[12];
  const int*   pos    = (const int*)d_in[13];

  float* hres = (float*)d_out;
  const size_t rows = (size_t)B_ * S_;  // 4096

  unsigned short* wQ    = (unsigned short*)d_ws;          // [L][3072][1024]
  unsigned short* wP    = wQ  + (size_t)2 * 3072 * 1024;  // [L][1024][1024]
  unsigned short* wF1   = wP  + (size_t)2 * 1024 * 1024;  // [L][4096][1024]
  unsigned short* wF2   = wF1 + (size_t)2 * 4096 * 1024;  // [L][1024][4096]
  unsigned short* xbf   = wF2 + (size_t)2 * 1024 * 4096;  // [4096][1024]
  unsigned short* qkvbf = xbf + rows * H_;                // [4096][3072]
  unsigned short* midbf = qkvbf + rows * 3 * H_;          // [4096][4096]
  unsigned short* aoutbf= midbf + rows * MLPH_;           // [4096][1024]
  float2* rtab = (float2*)(aoutbf + rows * H_);           // [S][32] cos/sin

  rope_tab_init<<<128, 256, 0, stream>>>(pos, rtab);
  wconv_all<<<24576, 256, 0, stream>>>(attn_w, proj_w, fc_w, fc2_w, wQ, wP, wF1, wF2);

  for (int l = 0; l < 2; l++) {
    const float* hin = (l == 0) ? hs : hres;  // l=0: read input directly
    ln_kernel<<<rows, 256, 0, stream>>>(hin, ln1_g + l * H_, ln1_b + l * H_, xbf);
    gemm_mfma<3, 4><<<dim3(24, 32), 256, 0, stream>>>(
        xbf, wQ + (size_t)l * 3072 * 1024, attn_b + (size_t)l * 3072, nullptr,
        qkvbf, 4096, 3072, 1024, rtab);
    attn9<<<dim3(16, 16, 4), 256, 0, stream>>>(qkvbf, aoutbf);
    gemm_mfma<2, 2><<<dim3(16, 32), 256, 0, stream>>>(
        aoutbf, wP + (size_t)l * 1024 * 1024, proj_b + (size_t)l * 1024, hin,
        hres, 4096, 1024, 1024, nullptr);
    ln_kernel<<<rows, 256, 0, stream>>>(hres, ln2_g + l * H_, ln2_b + l * H_, xbf);
    gemm_mfma<1, 4><<<dim3(32, 32), 256, 0, stream>>>(
        xbf, wF1 + (size_t)l * 4096 * 1024, fc_b + (size_t)l * 4096, nullptr,
        midbf, 4096, 4096, 1024, nullptr);
    gemm_mfma<2, 2><<<dim3(16, 32), 256, 0, stream>>>(
        midbf, wF2 + (size_t)l * 1024 * 4096, fc2_b + (size_t)l * 1024, hres,
        hres, 4096, 1024, 4096, nullptr);
  }
}

// Round 20
// 394.114 us; speedup vs baseline: 1.1929x; 1.0155x over previous
//
#include <hip/hip_runtime.h>

#define B_ 4
#define S_ 1024
#define H_ 1024
#define NH_ 16
#define DK_ 64
#define MLPH_ 4096
#define EPS_ 1e-5f

typedef __attribute__((ext_vector_type(8))) short short8_t;
typedef __attribute__((ext_vector_type(8))) unsigned short ushort8_t;
typedef __attribute__((ext_vector_type(4))) float f32x4;

__device__ __forceinline__ unsigned short f2bf(float f) {
  unsigned int u = __float_as_uint(f);
  u = u + 0x7fffu + ((u >> 16) & 1u);  // RNE
  return (unsigned short)(u >> 16);
}
__device__ __forceinline__ float bf2f(unsigned short b) {
  return __uint_as_float(((unsigned int)b) << 16);
}

__device__ __forceinline__ void gload16(const void* g, void* l) {
  typedef const __attribute__((address_space(1))) unsigned int GU;
  typedef __attribute__((address_space(3))) unsigned int LU;
  __builtin_amdgcn_global_load_lds((GU*)(size_t)g, (LU*)(unsigned int)(size_t)l, 16, 0, 0);
}

// gelu_tanh via sigmoid identity: 0.5x(1+tanh(u)) = x*sigma(2u). Overflow-safe.
__device__ __forceinline__ float gelu_tanh(float x) {
  float y = 1.5957691216057308f * (x + 0.044715f * x * x * x);
  return x / (1.0f + __expf(-y));
}

// ---------------- merged setup: weight converts (24576 tiles) + RoPE table (128) ----
// fp32 [K,N] -> bf16 [N,K], 32x32 tiles. Tile ranges (x2 layers):
//   attn 6144 | proj 2048 | fc1 8192 | fc2 8192 | rope-table blocks 24576..24703.
__global__ __launch_bounds__(256) void wconv_all(
    const float* __restrict__ s0, const float* __restrict__ s1,
    const float* __restrict__ s2, const float* __restrict__ s3,
    unsigned short* __restrict__ d0, unsigned short* __restrict__ d1,
    unsigned short* __restrict__ d2, unsigned short* __restrict__ d3,
    const int* __restrict__ pos, float2* __restrict__ tab) {
  __shared__ float t[32][33];
  int bid = blockIdx.x;
  if (bid >= 24576) {
    int idx = (bid - 24576) * 256 + threadIdx.x;  // over S*32
    int d2i = idx & 31, s = idx >> 5;
    float invf = __expf(-0.2878231366242557f * (float)d2i);  // 10000^(-d2/32)
    float th = (float)pos[s] * invf;
    float sn, cs;
    __sincosf(th, &sn, &cs);
    tab[idx] = make_float2(cs, sn);
    return;
  }
  const float* src; unsigned short* dst; int K, N, local;
  if (bid < 6144)        { src = s0; dst = d0; K = 1024; N = 3072; local = bid; }
  else if (bid < 8192)   { src = s1; dst = d1; K = 1024; N = 1024; local = bid - 6144; }
  else if (bid < 16384)  { src = s2; dst = d2; K = 1024; N = 4096; local = bid - 8192; }
  else                   { src = s3; dst = d3; K = 4096; N = 1024; local = bid - 16384; }
  int tiles = (N >> 5) * (K >> 5);
  int layer = (local >= tiles) ? 1 : 0;
  int tl = local - layer * tiles;
  src += (size_t)layer * K * N;
  dst += (size_t)layer * N * K;
  int n0 = (tl % (N >> 5)) * 32, k0 = (tl / (N >> 5)) * 32;
  int tid = threadIdx.x;
  int r = tid >> 3, c = (tid & 7) * 4;
  const float* s = src + (size_t)(k0 + r) * N + n0 + c;
  float4 v = *(const float4*)s;
  t[r][c] = v.x; t[r][c + 1] = v.y; t[r][c + 2] = v.z; t[r][c + 3] = v.w;
  __syncthreads();
  ushort4 o;
  o.x = f2bf(t[c + 0][r]); o.y = f2bf(t[c + 1][r]);
  o.z = f2bf(t[c + 2][r]); o.w = f2bf(t[c + 3][r]);
  *(ushort4*)(dst + (size_t)(n0 + r) * K + k0 + c) = o;
}

// ---------------- LayerNorm: block per row, 256 thr x float4, LDS reduce ----------------
__global__ __launch_bounds__(256) void ln_kernel(const float* __restrict__ x,
                                                 const float* __restrict__ g,
                                                 const float* __restrict__ b,
                                                 unsigned short* __restrict__ y) {
  int row = blockIdx.x, tid = threadIdx.x;
  const float* xp = x + (size_t)row * H_;
  float4 v = *((const float4*)xp + tid);
  float s  = v.x + v.y + v.z + v.w;
  float s2 = v.x * v.x + v.y * v.y + v.z * v.z + v.w * v.w;
  #pragma unroll
  for (int o = 1; o < 64; o <<= 1) {
    s  += __shfl_xor(s, o, 64);
    s2 += __shfl_xor(s2, o, 64);
  }
  __shared__ float r1[4], r2[4];
  if ((tid & 63) == 0) { r1[tid >> 6] = s; r2[tid >> 6] = s2; }
  __syncthreads();
  s  = r1[0] + r1[1] + r1[2] + r1[3];
  s2 = r2[0] + r2[1] + r2[2] + r2[3];
  float mean = s * (1.0f / H_);
  float var  = s2 * (1.0f / H_) - mean * mean;
  float inv  = rsqrtf(var + EPS_);
  float4 gv = *((const float4*)g + tid);
  float4 bv = *((const float4*)b + tid);
  ushort4 o;
  o.x = f2bf((v.x - mean) * inv * gv.x + bv.x);
  o.y = f2bf((v.y - mean) * inv * gv.y + bv.y);
  o.z = f2bf((v.z - mean) * inv * gv.z + bv.z);
  o.w = f2bf((v.w - mean) * inv * gv.w + bv.w);
  *(ushort4*)(y + (size_t)row * H_ + tid * 4) = o;
}

// ---------------- bf16 MFMA GEMM: 128xBN tile, BK=64, 4 waves, 2-phase dbuf ----------------
// Known-good: stage(t+1) before compute(t), one __syncthreads per tile; 2D-rect
// XCD swizzle (per-XCD L2 working set ~6.3MB); conflict-free 8-slot XOR swizzle.
// MODE 0: bf16=A*W+bias; 1: gelu; 2: f32=resid+...; 3: qkv w/ fused RoPE (table).
template <int MODE, int NT>
__global__ __launch_bounds__(256) void gemm_mfma(
    const unsigned short* __restrict__ A, const unsigned short* __restrict__ Bt,
    const float* __restrict__ bias, const float* __restrict__ resid,
    void* __restrict__ outp, int M, int N, int K, const float2* __restrict__ rtab) {
  constexpr int BN = NT * 32;
  constexpr int CB = BN / 32;  // B chunks (8 rows) per wave
  __shared__ __align__(16) unsigned short As[2][128 * 64];
  __shared__ __align__(16) unsigned short Bs[2][BN * 64];
  int tid = threadIdx.x;
  int w = tid >> 6, lane = tid & 63;
  // 2D XCD swizzle: 4x2 rectangles over (m-tiles) x (n-tiles)
  int gx = gridDim.x;
  int bid = blockIdx.y * gx + blockIdx.x;
  int xcd = bid & 7, r = bid >> 3;
  int rw = gx >> 1;
  int ry = xcd >> 1, rx = xcd & 1;
  int lm = r / rw, ln = r % rw;
  int m0 = (ry * (gridDim.y >> 2) + lm) * 128;
  int n0 = (rx * rw + ln) * BN;
  int wr = w >> 1, wc = w & 1;
  int fr = lane & 15, kg = lane >> 4;
  f32x4 acc[4][NT];
  #pragma unroll
  for (int m = 0; m < 4; m++)
    #pragma unroll
    for (int n = 0; n < NT; n++) {
      acc[m][n][0] = 0.f; acc[m][n][1] = 0.f; acc[m][n][2] = 0.f; acc[m][n][3] = 0.f;
    }
  int srow = lane >> 3;
  int scol = ((lane & 7) ^ srow) * 8;  // pre-swizzled global source
  const unsigned short* Ap = A  + (size_t)(m0 + w * 32 + srow) * K + scol;
  const unsigned short* Bp = Bt + (size_t)(n0 + w * (8 * CB) + srow) * K + scol;
  int sx = (fr & 7);  // read-side swizzle key
  int nk = K >> 6;
  // prologue: stage tile 0 -> buf 0
  {
    char* AsB = (char*)As[0] + w * 4096;
    char* BsB = (char*)Bs[0] + w * CB * 1024;
    #pragma unroll
    for (int i = 0; i < 4; i++) gload16(Ap + (size_t)i * 8 * K, AsB + i * 1024);
    #pragma unroll
    for (int i = 0; i < CB; i++) gload16(Bp + (size_t)i * 8 * K, BsB + i * 1024);
  }
  __syncthreads();
  for (int t = 0; t < nk; t++) {
    int cur = t & 1;
    if (t + 1 < nk) {
      const unsigned short* Ap2 = Ap + (size_t)(t + 1) * 64;
      const unsigned short* Bp2 = Bp + (size_t)(t + 1) * 64;
      char* AsB = (char*)As[cur ^ 1] + w * 4096;
      char* BsB = (char*)Bs[cur ^ 1] + w * CB * 1024;
      #pragma unroll
      for (int i = 0; i < 4; i++) gload16(Ap2 + (size_t)i * 8 * K, AsB + i * 1024);
      #pragma unroll
      for (int i = 0; i < CB; i++) gload16(Bp2 + (size_t)i * 8 * K, BsB + i * 1024);
    }
    #pragma unroll
    for (int kk = 0; kk < 2; kk++) {
      int slot = ((kk * 4 + kg) ^ sx) << 4;
      short8_t af[4], bfr[NT];
      #pragma unroll
      for (int m = 0; m < 4; m++)
        af[m] = *(const short8_t*)((char*)As[cur] + (wr * 64 + m * 16 + fr) * 128 + slot);
      #pragma unroll
      for (int n = 0; n < NT; n++)
        bfr[n] = *(const short8_t*)((char*)Bs[cur] + (wc * (NT * 16) + n * 16 + fr) * 128 + slot);
      #pragma unroll
      for (int m = 0; m < 4; m++)
        #pragma unroll
        for (int n = 0; n < NT; n++)
          acc[m][n] = __builtin_amdgcn_mfma_f32_16x16x32_bf16(af[m], bfr[n], acc[m][n], 0, 0, 0);
    }
    __syncthreads();
  }

  if (MODE == 3) {
    int seg = n0 >> 10;  // 0=q, 1=k, 2=v
    if (seg < 2) {
      #pragma unroll
      for (int n = 0; n < 2; n++) {
        int col0 = n0 + wc * 64 + n * 16 + fr;
        int d2 = n * 16 + fr;
        float bv0 = bias[col0], bv2 = bias[col0 + 32];
        #pragma unroll
        for (int m = 0; m < 4; m++) {
          int row = m0 + wr * 64 + m * 16 + kg * 4;
          #pragma unroll
          for (int r2 = 0; r2 < 4; r2++) {
            int s = (row + r2) & (S_ - 1);
            float2 cssn = rtab[(s << 5) + d2];
            float a0 = acc[m][n][r2] + bv0;
            float a2 = acc[m][n + 2][r2] + bv2;
            size_t base = (size_t)(row + r2) * N;
            ((unsigned short*)outp)[base + col0]      = f2bf(a0 * cssn.x - a2 * cssn.y);
            ((unsigned short*)outp)[base + col0 + 32] = f2bf(a2 * cssn.x + a0 * cssn.y);
          }
        }
      }
    } else {
      #pragma unroll
      for (int n = 0; n < NT; n++) {
        int col = n0 + wc * (NT * 16) + n * 16 + fr;
        float bv = bias[col];
        #pragma unroll
        for (int m = 0; m < 4; m++) {
          int row = m0 + wr * 64 + m * 16 + kg * 4;
          #pragma unroll
          for (int r2 = 0; r2 < 4; r2++)
            ((unsigned short*)outp)[(size_t)(row + r2) * N + col] = f2bf(acc[m][n][r2] + bv);
        }
      }
    }
    return;
  }
  #pragma unroll
  for (int n = 0; n < NT; n++) {
    int col = n0 + wc * (NT * 16) + n * 16 + fr;
    float bv = bias[col];
    #pragma unroll
    for (int m = 0; m < 4; m++) {
      int row = m0 + wr * 64 + m * 16 + kg * 4;
      #pragma unroll
      for (int r2 = 0; r2 < 4; r2++) {
        float v = acc[m][n][r2] + bv;
        size_t idx = (size_t)(row + r2) * N + col;
        if (MODE == 2)      ((float*)outp)[idx] = resid[idx] + v;
        else if (MODE == 1) ((unsigned short*)outp)[idx] = f2bf(gelu_tanh(v));
        else                ((unsigned short*)outp)[idx] = f2bf(v);
      }
    }
  }
}

// ---------------- MFMA flash attention v9: QBLK=64, 4 blocks/CU, quad-balanced ----------------
__global__ __launch_bounds__(256) void attn9(const unsigned short* __restrict__ qkv,
                                             unsigned short* __restrict__ aout) {
  __shared__ __align__(16) unsigned short Ks[2][64 * 64];   // [kv][d], swizzled
  __shared__ __align__(16) unsigned short Vt[2][64 * 64];   // [d][kv], swizzled
  __shared__ __align__(16) unsigned short Ps[4][16 * 64];   // [q][kv], swizzled
  const float SCL2 = 0.18033688011112443f;  // 0.125 * log2(e)
  const float THR2 = 11.541560327111708f;   // 8 * log2(e)
  int tid = threadIdx.x;
  int w = tid >> 6, lane = tid & 63;
  int fr = lane & 15, kg = lane >> 4;
  // quad-balanced bijective remap over (qt, head, b)
  int lid = ((blockIdx.z << 4) + blockIdx.y) * 16 + blockIdx.x;  // 0..1023
  int phase = lid >> 8, s256 = lid & 255;
  int i = s256 >> 6, combo = s256 & 63;
  int qt;
  if (phase == 0)      qt = 15 - i;
  else if (phase == 1) qt = i;
  else if (phase == 2) qt = 11 - i;
  else                 qt = 4 + i;
  int head = combo & 15, b = combo >> 4;
  int q0 = qt * 64;
  const unsigned short* base = qkv + ((size_t)b * S_) * 3072 + head * 64;

  const unsigned short* qp = base + (size_t)(q0 + w * 16 + fr) * 3072 + kg * 8;
  short8_t qa0 = *(const short8_t*)qp;
  short8_t qa1 = *(const short8_t*)(qp + 32);

  f32x4 acc[4];  // O^T: [d-tile n]: lane holds d=kg*4+j, q=fr
  float mrun = -3.0e38f, lrun = 0.f;
  #pragma unroll
  for (int n = 0; n < 4; n++) {
    acc[n][0] = 0.f; acc[n][1] = 0.f; acc[n][2] = 0.f; acc[n][3] = 0.f;
  }

  int skv = lane;       // staging: kv row
  int sd0 = w * 16;     // staging: dk offset
  int qrow = q0 + w * 16 + fr;

  const unsigned short* kp0 = base + 1024 + (size_t)skv * 3072 + sd0;
  short8_t ka = *(const short8_t*)kp0;
  short8_t kb = *(const short8_t*)(kp0 + 8);
  short8_t va = *(const short8_t*)(kp0 + 1024);
  short8_t vb = *(const short8_t*)(kp0 + 1032);

  int ntiles = qt + 1;
  for (int t = 0; t < ntiles; t++) {
    int cur = t & 1;
    {
      unsigned kbyte = skv * 128 + sd0 * 2;
      unsigned ksw = (skv & 7) << 4;
      *(short8_t*)((char*)Ks[cur] + (kbyte ^ ksw)) = ka;
      *(short8_t*)((char*)Ks[cur] + ((kbyte + 16) ^ ksw)) = kb;
      #pragma unroll
      for (int j = 0; j < 8; j++) {
        int d0 = sd0 + j, d1 = sd0 + 8 + j;
        *(unsigned short*)((char*)Vt[cur] + ((d0 * 128 + skv * 2) ^ ((d0 & 7) << 4))) = (unsigned short)va[j];
        *(unsigned short*)((char*)Vt[cur] + ((d1 * 128 + skv * 2) ^ ((d1 & 7) << 4))) = (unsigned short)vb[j];
      }
    }
    if (t + 1 < ntiles) {
      const unsigned short* kp = base + 1024 + (size_t)((t + 1) * 64 + skv) * 3072 + sd0;
      ka = *(const short8_t*)kp;
      kb = *(const short8_t*)(kp + 8);
      va = *(const short8_t*)(kp + 1024);
      vb = *(const short8_t*)(kp + 1032);
    }
    __syncthreads();
    // ---- K and V fragments issued together: V latency hides under QK+softmax ----
    short8_t b0[4], b1[4], v0[4], v1[4];
    #pragma unroll
    for (int n = 0; n < 4; n++) {
      int kvrow = n * 16 + fr;
      unsigned sw = (kvrow & 7) << 4;
      b0[n] = *(const short8_t*)((char*)Ks[cur] + ((kvrow * 128 + kg * 16) ^ sw));
      b1[n] = *(const short8_t*)((char*)Ks[cur] + ((kvrow * 128 + 64 + kg * 16) ^ sw));
    }
    #pragma unroll
    for (int n = 0; n < 4; n++) {
      int d = n * 16 + fr;
      unsigned sw = (d & 7) << 4;
      v0[n] = *(const short8_t*)((char*)Vt[cur] + ((d * 128 + kg * 16) ^ sw));
      v1[n] = *(const short8_t*)((char*)Vt[cur] + ((d * 128 + 64 + kg * 16) ^ sw));
    }
    // ---- QK^T swapped: st[n]; lane: q=fr, kv=n*16+kg*4+j ----
    f32x4 st[4];
    __builtin_amdgcn_s_setprio(1);
    #pragma unroll
    for (int n = 0; n < 4; n++) {
      f32x4 z; z[0] = 0.f; z[1] = 0.f; z[2] = 0.f; z[3] = 0.f;
      z = __builtin_amdgcn_mfma_f32_16x16x32_bf16(b0[n], qa0, z, 0, 0, 0);
      z = __builtin_amdgcn_mfma_f32_16x16x32_bf16(b1[n], qa1, z, 0, 0, 0);
      st[n] = z;
    }
    __builtin_amdgcn_s_setprio(0);
    // ---- softmax (exp2 domain), defer-max, per-lane scalars ----
    bool diag = (t == qt);
    float rm = -3.0e38f;
    #pragma unroll
    for (int n = 0; n < 4; n++)
      #pragma unroll
      for (int j = 0; j < 4; j++) {
        float sv = st[n][j] * SCL2;
        if (diag && (t * 64 + n * 16 + kg * 4 + j > qrow)) sv = -1.0e30f;
        st[n][j] = sv;
        rm = fmaxf(rm, sv);
      }
    if (__any(rm > mrun + THR2)) {
      rm = fmaxf(rm, __shfl_xor(rm, 16, 64));
      rm = fmaxf(rm, __shfl_xor(rm, 32, 64));
      float mn = fmaxf(mrun, rm);
      float sc = exp2f(mrun - mn);
      mrun = mn;
      lrun *= sc;
      #pragma unroll
      for (int n = 0; n < 4; n++) {
        acc[n][0] *= sc; acc[n][1] *= sc; acc[n][2] *= sc; acc[n][3] *= sc;
      }
    }
    {
      float ls = 0.f;
      #pragma unroll
      for (int n = 0; n < 4; n++) {
        float e0 = exp2f(st[n][0] - mrun);
        float e1 = exp2f(st[n][1] - mrun);
        float e2 = exp2f(st[n][2] - mrun);
        float e3 = exp2f(st[n][3] - mrun);
        ls += (e0 + e1) + (e2 + e3);
        unsigned lo, hi;
        asm("v_cvt_pk_bf16_f32 %0, %1, %2" : "=v"(lo) : "v"(e0), "v"(e1));
        asm("v_cvt_pk_bf16_f32 %0, %1, %2" : "=v"(hi) : "v"(e2), "v"(e3));
        uint2 pk; pk.x = lo; pk.y = hi;
        *(uint2*)((char*)Ps[w] + ((fr * 128 + n * 32 + kg * 8) ^ ((fr & 7) << 4))) = pk;
      }
      lrun += ls;
    }
    asm volatile("s_waitcnt lgkmcnt(0)" ::: "memory");
    // ---- PV swapped: acc += mfma(V^T, P^T); V already in regs ----
    unsigned psw = (fr & 7) << 4;
    short8_t pa0 = *(const short8_t*)((char*)Ps[w] + ((fr * 128 + kg * 16) ^ psw));
    short8_t pa1 = *(const short8_t*)((char*)Ps[w] + ((fr * 128 + 64 + kg * 16) ^ psw));
    __builtin_amdgcn_s_setprio(1);
    #pragma unroll
    for (int n = 0; n < 4; n++) {
      acc[n] = __builtin_amdgcn_mfma_f32_16x16x32_bf16(v0[n], pa0, acc[n], 0, 0, 0);
      acc[n] = __builtin_amdgcn_mfma_f32_16x16x32_bf16(v1[n], pa1, acc[n], 0, 0, 0);
    }
    __builtin_amdgcn_s_setprio(0);
  }
  // ---- epilogue: O^T -> out; lane q=fr, d = n*16+kg*4+j ----
  {
    float ls = lrun;
    ls += __shfl_xor(ls, 16, 64);
    ls += __shfl_xor(ls, 32, 64);
    float inv = 1.0f / ls;
    size_t row = (size_t)b * S_ + q0 + w * 16 + fr;
    unsigned short* op = aout + row * H_ + head * 64 + kg * 4;
    #pragma unroll
    for (int n = 0; n < 4; n++) {
      ushort4 o;
      o.x = f2bf(acc[n][0] * inv);
      o.y = f2bf(acc[n][1] * inv);
      o.z = f2bf(acc[n][2] * inv);
      o.w = f2bf(acc[n][3] * inv);
      *(ushort4*)(op + n * 16) = o;
    }
  }
}

extern "C" void kernel_launch(void* const* d_in, const int* in_sizes, int n_in,
                              void* d_out, int out_size, void* d_ws, size_t ws_size,
                              hipStream_t stream) {
  const float* hs     = (const float*)d_in[0];
  const float* attn_w = (const float*)d_in[1];
  const float* attn_b = (const float*)d_in[2];
  const float* proj_w = (const float*)d_in[3];
  const float* proj_b = (const float*)d_in[4];
  const float* fc_w   = (const float*)d_in[5];
  const float* fc_b   = (const float*)d_in[6];
  const float* fc2_w  = (const float*)d_in[7];
  const float* fc2_b  = (const float*)d_in[8];
  const float* ln1_g  = (const float*)d_in[9];
  const float* ln1_b  = (const float*)d_in[10];
  const float* ln2_g  = (const float*)d_in[11];
  const float* ln2_b  = (const float*)d_in[12];
  const int*   pos    = (const int*)d_in[13];

  float* hres = (float*)d_out;
  const size_t rows = (size_t)B_ * S_;  // 4096

  unsigned short* wQ    = (unsigned short*)d_ws;          // [L][3072][1024]
  unsigned short* wP    = wQ  + (size_t)2 * 3072 * 1024;  // [L][1024][1024]
  unsigned short* wF1   = wP  + (size_t)2 * 1024 * 1024;  // [L][4096][1024]
  unsigned short* wF2   = wF1 + (size_t)2 * 4096 * 1024;  // [L][1024][4096]
  unsigned short* xbf   = wF2 + (size_t)2 * 1024 * 4096;  // [4096][1024]
  unsigned short* qkvbf = xbf + rows * H_;                // [4096][3072]
  unsigned short* midbf = qkvbf + rows * 3 * H_;          // [4096][4096]
  unsigned short* aoutbf= midbf + rows * MLPH_;           // [4096][1024]
  float2* rtab = (float2*)(aoutbf + rows * H_);           // [S][32] cos/sin

  wconv_all<<<24704, 256, 0, stream>>>(attn_w, proj_w, fc_w, fc2_w,
                                       wQ, wP, wF1, wF2, pos, rtab);

  for (int l = 0; l < 2; l++) {
    const float* hin = (l == 0) ? hs : hres;  // l=0: read input directly
    ln_kernel<<<rows, 256, 0, stream>>>(hin, ln1_g + l * H_, ln1_b + l * H_, xbf);
    gemm_mfma<3, 4><<<dim3(24, 32), 256, 0, stream>>>(
        xbf, wQ + (size_t)l * 3072 * 1024, attn_b + (size_t)l * 3072, nullptr,
        qkvbf, 4096, 3072, 1024, rtab);
    attn9<<<dim3(16, 16, 4), 256, 0, stream>>>(qkvbf, aoutbf);
    gemm_mfma<2, 2><<<dim3(16, 32), 256, 0, stream>>>(
        aoutbf, wP + (size_t)l * 1024 * 1024, proj_b + (size_t)l * 1024, hin,
        hres, 4096, 1024, 1024, nullptr);
    ln_kernel<<<rows, 256, 0, stream>>>(hres, ln2_g + l * H_, ln2_b + l * H_, xbf);
    gemm_mfma<1, 4><<<dim3(32, 32), 256, 0, stream>>>(
        xbf, wF1 + (size_t)l * 4096 * 1024, fc_b + (size_t)l * 4096, nullptr,
        midbf, 4096, 4096, 1024, nullptr);
    gemm_mfma<2, 2><<<dim3(16, 32), 256, 0, stream>>>(
        midbf, wF2 + (size_t)l * 1024 * 4096, fc2_b + (size_t)l * 1024, hres,
        hres, 4096, 1024, 4096, nullptr);
  }
}